// Round 9
// baseline (582.528 us; speedup 1.0000x reference)
//
#include <hip/hip_runtime.h>
#include <hip/hip_bf16.h>

typedef _Float16 f16;
typedef _Float16 f16x8 __attribute__((ext_vector_type(8)));
typedef _Float16 f16x4 __attribute__((ext_vector_type(4)));
typedef _Float16 f16x2 __attribute__((ext_vector_type(2)));
typedef float f32x4 __attribute__((ext_vector_type(4)));
typedef float f32x2 __attribute__((ext_vector_type(2)));

#define MFMA16(a, b, c) __builtin_amdgcn_mfma_f32_16x16x32_f16((a), (b), (c), 0, 0, 0)

__device__ __forceinline__ void load16(const void* g, void* l) {
    __builtin_amdgcn_global_load_lds((const __attribute__((address_space(1))) void*)g,
                                     (__attribute__((address_space(3))) void*)l, 16, 0, 0);
}

__device__ __forceinline__ unsigned int pkrtz(float a, float b) {
    return __builtin_bit_cast(unsigned int, __builtin_amdgcn_cvt_pkrtz(a, b));
}

// ---------------------------------------------------------------- prep (fused)
// R6 layout (NO Wout-fold here: folding it into prep cost ~35us twice, R5/R7 —
// the 256-iter serial-loop blocks straggle at the tail of the dispatch).
// blocks 0..8191      : x0,x1 fp32 -> xh f16
// blocks 8192..8703   : wcat_t[n][k] = [Wqk^T; Wv^T]
// blocks 8704..9215   : w1t[n][k<256] = W1_top^T
// blocks 9216..9727   : w1bt[n][t] = W1[256+t][n]
// blocks 9728..10239  : w2t[n][k] = W2[k][n]
// blocks 10240..10495 : woutf16 = (f16)Wout
// blocks 10496..11007 : bias_eff[n] = b1[n] + sum_j bout[j]*W1[256+j][n]
__global__ __launch_bounds__(256) void k_prep(const float* __restrict__ x0,
                                              const float* __restrict__ x1,
                                              const float* __restrict__ Wqk,
                                              const float* __restrict__ Wv,
                                              const float* __restrict__ W1,
                                              const float* __restrict__ W2,
                                              const float* __restrict__ Wout,
                                              const float* __restrict__ b1,
                                              const float* __restrict__ bout,
                                              f16* __restrict__ xh, f16* __restrict__ wcat_t,
                                              f16* __restrict__ w1t, f16* __restrict__ w1bt,
                                              f16* __restrict__ w2t, f16* __restrict__ woutf16,
                                              float* __restrict__ bias_eff) {
    __shared__ float red[4];
    const int blk = blockIdx.x, tid = threadIdx.x;
    if (blk < 8192) {
        size_t i = ((size_t)blk * 256 + tid) * 4;
        const float* src = (i < 4194304) ? (x0 + i) : (x1 + (i - 4194304));
        float4 v = *(const float4*)src;
        f16x4 o = {(f16)v.x, (f16)v.y, (f16)v.z, (f16)v.w};
        *(f16x4*)(xh + i) = o;
    } else if (blk < 8704) {
        int n = blk - 8192;
        const float* W = (n < 256) ? Wqk : Wv;
        wcat_t[n * 256 + tid] = (f16)W[tid * 256 + (n & 255)];
    } else if (blk < 9216) {
        int n = blk - 8704;
        w1t[n * 512 + tid] = (f16)W1[tid * 512 + n];
    } else if (blk < 9728) {
        int n = blk - 9216;
        w1bt[n * 256 + tid] = (f16)W1[(256 + tid) * 512 + n];
    } else if (blk < 10240) {
        int j = blk - 9728;
        int n = j >> 1, k = (j & 1) * 256 + tid;
        w2t[n * 512 + k] = (f16)W2[k * 256 + n];
    } else if (blk < 10496) {
        int o = (blk - 10240) * 256 + tid;
        woutf16[o] = (f16)Wout[o];
    } else {
        int n = blk - 10496;
        float s = bout[tid] * W1[(size_t)(256 + tid) * 512 + n];
#pragma unroll
        for (int off = 1; off < 64; off <<= 1) s += __shfl_xor(s, off);
        int wave = tid >> 6, lane = tid & 63;
        if (lane == 0) red[wave] = s;
        __syncthreads();
        if (tid == 0) bias_eff[n] = b1[n] + red[0] + red[1] + red[2] + red[3];
    }
}

// ---------------------------------------------------------------- GEMM, 128m x 256n tile
// C[M][N] = A[M][K] (f16) @ Bt[N][K]^T (f16), fp32 accum. Wide n-tile halves the
// number of bn passes -> halves A re-fetch traffic (FFN1 256->128 MB; FFN2
// single-pass). Grid x = bm (fast): bm%8 pins a row-tile's passes to one XCD.
// mode 0: proj  -> bn0=0: (v+bqk)*scale to qk (2,B,H,L,D); bn0=256: v+bv to vt (2,B,H,D,L)
// mode 2: f16 out [M][N] = v + bias1[n]
// mode 3: f32 out [M][256] = v + bias1[n] + (float)resh[m][n]
// mode 4: f16 out[m][256+n] stride 512, no bias (WoW1b -> w1t right half)
// R12: WoW1b piggyback — when pgOut != nullptr, blocks x>=256 (y==0) run the
// WoW1b GEMM (M=512,N=256,K=256) with substituted params; saves its dispatch.
// R14: qk-half operand swap — mode 0 / y==0 computes MFMA(af,bf) so n lands in
// l16 (lanes = 16 consecutive d -> 32B-contiguous store runs) and m in quad*4+i
// (4 scalar stores @128B stride). Write sector amplification 8x -> 2x on the
// 16.8MB qk output (~100MB less HBM write traffic). vt half already 2x.
__global__ __launch_bounds__(256, 2) void k_gemm(const f16* __restrict__ A1,
                                                 const f16* __restrict__ A2, int ksplit,
                                                 int strideA, const f16* __restrict__ Bt, int K,
                                                 int N, const float* __restrict__ bias1,
                                                 const float* __restrict__ bias2, int mode,
                                                 void* __restrict__ out1, void* __restrict__ out2,
                                                 const f16* __restrict__ resh,
                                                 const f16* __restrict__ pgA,
                                                 const f16* __restrict__ pgBt,
                                                 f16* __restrict__ pgOut) {
    int bm0 = blockIdx.x * 128;
    int bn0 = blockIdx.y * 256;
    if (pgOut != nullptr && blockIdx.x >= 256) {
        if (blockIdx.y != 0) return;
        A1 = pgA;
        A2 = pgA;
        ksplit = 1 << 30;
        strideA = 256;
        Bt = pgBt;
        K = 256;
        N = 256;
        bias1 = nullptr;
        bias2 = nullptr;
        mode = 4;
        out1 = pgOut;
        out2 = nullptr;
        resh = nullptr;
        bm0 = (blockIdx.x - 256) * 128;
        bn0 = 0;
    }
    const bool swp = (mode == 0) && (blockIdx.y == 0);  // qk half: swapped operands
    __shared__ f16 As[2][4096];  // [128 rows][32 k] 16B chunks, chunk ^ (row&3)
    __shared__ f16 Bs[2][8192];  // [256 rows][32 k]
    const int tid = threadIdx.x;
    const int lane = tid & 63, wave = tid >> 6;
    const int quad = lane >> 4, l16 = lane & 15;
    const int wm0 = (wave & 1) * 64, wn0 = (wave >> 1) * 128;
    const int axor = l16 & 3;

    f32x4 acc[4][8];
#pragma unroll
    for (int tm = 0; tm < 4; tm++)
#pragma unroll
        for (int tn = 0; tn < 8; tn++) acc[tm][tn] = (f32x4){0.f, 0.f, 0.f, 0.f};

    auto stage = [&](int buf, int kt) {
        const int k0 = kt * 32;
        const f16* Ab = (k0 < ksplit) ? A1 : A2;
        const int koff = (k0 < ksplit) ? k0 : k0 - ksplit;
#pragma unroll
        for (int rd = 0; rd < 2; rd++) {
            const int cbase = rd * 256 + wave * 64;
            const int c = cbase + lane;
            const int row = c >> 2, col = (c & 3) ^ (row & 3);
            load16(Ab + (size_t)(bm0 + row) * strideA + koff + col * 8, &As[buf][cbase * 8]);
        }
#pragma unroll
        for (int rd = 0; rd < 4; rd++) {
            const int cbase = rd * 256 + wave * 64;
            const int c = cbase + lane;
            const int row = c >> 2, col = (c & 3) ^ (row & 3);
            load16(Bt + (size_t)(bn0 + row) * K + k0 + col * 8, &Bs[buf][cbase * 8]);
        }
    };

    const int NT = K >> 5;
    stage(0, 0);
    __syncthreads();
    for (int kt = 0; kt < NT; kt++) {
        const int cur = kt & 1;
        if (kt + 1 < NT) stage(cur ^ 1, kt + 1);
        f16x8 af[4], bf[8];
#pragma unroll
        for (int t = 0; t < 4; t++)
            af[t] = *(const f16x8*)&As[cur][(wm0 + t * 16 + l16) * 32 + (quad ^ axor) * 8];
#pragma unroll
        for (int t = 0; t < 8; t++)
            bf[t] = *(const f16x8*)&Bs[cur][(wn0 + t * 16 + l16) * 32 + (quad ^ axor) * 8];
        if (swp) {
#pragma unroll
            for (int tm = 0; tm < 4; tm++)
#pragma unroll
                for (int tn = 0; tn < 8; tn++)
                    acc[tm][tn] = MFMA16(af[tm], bf[tn], acc[tm][tn]);
        } else {
#pragma unroll
            for (int tm = 0; tm < 4; tm++)
#pragma unroll
                for (int tn = 0; tn < 8; tn++)
                    acc[tm][tn] = MFMA16(bf[tn], af[tm], acc[tm][tn]);
        }
        __syncthreads();
    }

    if (swp) {
        // swapped fragment: n = ...+l16 (lane-contiguous d), m = ...+quad*4+i
#pragma unroll
        for (int tm = 0; tm < 4; tm++) {
            const int m0 = bm0 + wm0 + tm * 16 + quad * 4;
            const int s = m0 >> 14, r14 = m0 & 16383, b = r14 >> 11, l0 = r14 & 2047;
#pragma unroll
            for (int tn = 0; tn < 8; tn++) {
                const int n = wn0 + tn * 16 + l16;  // bn0 == 0, n < 256
                const float bi = bias1[n];
                const int h = n >> 6, d = n & 63;
                const size_t hh = (size_t)((s * 8 + b) * 4 + h);
                f16* o = (f16*)out1 + (hh * 2048 + l0) * 64 + d;
                const f32x4 v = acc[tm][tn];
                o[0] = (f16)((v[0] + bi) * 0.42466090f);
                o[64] = (f16)((v[1] + bi) * 0.42466090f);
                o[128] = (f16)((v[2] + bi) * 0.42466090f);
                o[192] = (f16)((v[3] + bi) * 0.42466090f);
            }
        }
        return;
    }

#pragma unroll
    for (int tm = 0; tm < 4; tm++) {
        const int m = bm0 + wm0 + tm * 16 + l16;
#pragma unroll
        for (int tn = 0; tn < 8; tn++) {
            const int n = bn0 + wn0 + tn * 16 + quad * 4;
            f32x4 v = acc[tm][tn];
            if (mode == 0) {
                const int s = m >> 14, r14 = m & 16383, b = r14 >> 11, l = r14 & 2047;
                // y==0 handled by swp path; here n >= 256 always (vt half)
                const int n2 = n - 256;
                float4 bi = *(const float4*)(bias2 + n2);
                const int h = n2 >> 6, d = n2 & 63;
                const size_t hh = (size_t)((s * 8 + b) * 4 + h);
                f16* o2 = (f16*)out2 + (hh * 64 + d) * 2048 + l;
                o2[0] = (f16)(v[0] + bi.x);
                o2[2048] = (f16)(v[1] + bi.y);
                o2[4096] = (f16)(v[2] + bi.z);
                o2[6144] = (f16)(v[3] + bi.w);
            } else if (mode == 2) {
                float4 bi = *(const float4*)(bias1 + n);
                f16x4 o = {(f16)(v[0] + bi.x), (f16)(v[1] + bi.y), (f16)(v[2] + bi.z),
                           (f16)(v[3] + bi.w)};
                *(f16x4*)((f16*)out1 + (size_t)m * N + n) = o;
            } else if (mode == 3) {
                float4 bi = *(const float4*)(bias1 + n);
                f16x4 rr = *(const f16x4*)(resh + (size_t)m * 256 + n);
                float4 o = {v[0] + bi.x + (float)rr[0], v[1] + bi.y + (float)rr[1],
                            v[2] + bi.z + (float)rr[2], v[3] + bi.w + (float)rr[3]};
                *(float4*)((float*)out1 + (size_t)m * 256 + n) = o;
            } else {  // mode 4
                f16x4 o = {(f16)v[0], (f16)v[1], (f16)v[2], (f16)v[3]};
                *(f16x4*)((f16*)out1 + (size_t)m * 512 + 256 + n) = o;
            }
        }
    }
}

// ---------------------------------------------------------------- flash attention (S^T form)
// S^T = K Q^T. PV uses full-rate K=32 MFMA; B-operand built from adjacent 16-kv
// S^T fragments with permlane32/16 swaps (R8). R9 VALU diet. R11 ones-row MFMA
// row-sum. R13: T4 double-barrier counted-vmcnt (2 raw barriers/body, vmcnt(4),
// no drain in main loop). Unchanged in R14.
// Grid x=bh (fast): all 16 q-tiles of one K/V panel on one XCD -> L2-served.
__global__ __launch_bounds__(256, 4) void k_flash(const f16* __restrict__ qkbuf,
                                                  const f16* __restrict__ vtbuf,
                                                  f16* __restrict__ mbuf) {
    const int z = blockIdx.z;
    const int bh = blockIdx.x;  // b*4+h (fast dim -> XCD-panel affinity)
    const int qt = blockIdx.y;  // 0..15
    const size_t HSZ = 2048 * 64;
    const size_t SSZ = 32 * HSZ;
    const f16* Q = qkbuf + (z ? SSZ : 0) + bh * HSZ;
    const f16* Kp = qkbuf + (z ? 0 : SSZ) + bh * HSZ;
    const f16* Vt = vtbuf + (z ? 0 : SSZ) + bh * HSZ;
    f16* Mo = mbuf + (size_t)z * (16384 * 256);

    __shared__ f16 Ks[2][4096];  // 64 rows x 64 cols, xor-swizzled 16B chunks
    __shared__ f16 Vs[2][4096];  // 64 d-rows x 64 kv-cols, same swizzle

    const int tid = threadIdx.x, lane = tid & 63, wave = tid >> 6;
    const int quad = lane >> 4, l16 = lane & 15;
    const int srow = lane >> 3;
    const int slc = (lane & 7) ^ (srow & 7);
    const int sw = l16 & 7;

    const int q0 = qt * 128 + wave * 32;
    f16x8 qf[2][2];
#pragma unroll
    for (int tq = 0; tq < 2; tq++)
#pragma unroll
        for (int kk = 0; kk < 2; kk++)
            qf[tq][kk] =
                *(const f16x8*)(Q + (size_t)(q0 + tq * 16 + l16) * 64 + kk * 32 + quad * 8);

    // loop-invariant per-lane LDS read bases (elements). Reads add compile-time
    // buf*4096 + tile*1024 -> folded into ds_read offset immediates.
    const f16* kb[2] = {&Ks[0][l16 * 64 + ((0 + quad) ^ sw) * 8],
                        &Ks[0][l16 * 64 + ((4 + quad) ^ sw) * 8]};
    const f16* vb[2] = {&Vs[0][l16 * 64 + ((0 + quad) ^ sw) * 8],
                        &Vs[0][l16 * 64 + ((4 + quad) ^ sw) * 8]};

    // loop-invariant stage pointers (global per-lane src, wave-uniform LDS dst)
    const f16* pK0 = Kp + (size_t)(wave * 16 + srow) * 64 + slc * 8;
    const f16* pK1 = pK0 + 8 * 64;
    const f16* pV0 = Vt + (size_t)(wave * 16 + srow) * 2048 + slc * 8;
    const f16* pV1 = pV0 + 8 * 2048;
    f16* kd0 = &Ks[0][(wave * 2 + 0) * 512];
    f16* kd1 = &Ks[0][(wave * 2 + 1) * 512];
    f16* vd0 = &Vs[0][(wave * 2 + 0) * 512];
    f16* vd1 = &Vs[0][(wave * 2 + 1) * 512];

    auto stage = [&](int buf, int kv0) {
        load16(pK0 + (size_t)kv0 * 64, kd0 + buf * 4096);
        load16(pK1 + (size_t)kv0 * 64, kd1 + buf * 4096);
        load16(pV0 + kv0, vd0 + buf * 4096);
        load16(pV1 + kv0, vd1 + buf * 4096);
    };

    f32x4 oacc[4][2];
#pragma unroll
    for (int td = 0; td < 4; td++)
#pragma unroll
        for (int tq = 0; tq < 2; tq++) oacc[td][tq] = (f32x4){0.f, 0.f, 0.f, 0.f};
    f32x4 oext[2] = {{0.f, 0.f, 0.f, 0.f}, {0.f, 0.f, 0.f, 0.f}};  // ones-row l-sum
    const f16x8 vones = {(f16)1.f, (f16)1.f, (f16)1.f, (f16)1.f,
                         (f16)1.f, (f16)1.f, (f16)1.f, (f16)1.f};

    stage(0, 0);

    auto body = [&](int cur, int t) {
        if (t < 31) {
            stage(cur ^ 1, (t + 1) * 64);
            asm volatile("s_waitcnt vmcnt(4)" ::: "memory");  // cur's loads landed
        } else {
            asm volatile("s_waitcnt vmcnt(0)" ::: "memory");
        }
        __builtin_amdgcn_s_barrier();  // A: all waves' cur loads landed

        f32x4 sacc[4][2];
#pragma unroll
        for (int tkv = 0; tkv < 4; tkv++)
#pragma unroll
            for (int tq = 0; tq < 2; tq++)
                sacc[tkv][tq] = (f32x4){-8.f, -8.f, -8.f, -8.f};  // folds exp2(s-8)
#pragma unroll
        for (int kk = 0; kk < 2; kk++) {
#pragma unroll
            for (int tkv = 0; tkv < 4; tkv++) {
                f16x8 ka = *(const f16x8*)(kb[kk] + cur * 4096 + tkv * 1024);
#pragma unroll
                for (int tq = 0; tq < 2; tq++)
                    sacc[tkv][tq] = MFMA16(ka, qf[tq][kk], sacc[tkv][tq]);
            }
        }

        // P = exp2(sacc); pack to f16 (rtz); repack 16-kv pairs to K=32 B-frags
        f16x8 bfrag[2][2];  // [32-kv block][tq]
#pragma unroll
        for (int blk = 0; blk < 2; blk++) {
#pragma unroll
            for (int tq = 0; tq < 2; tq++) {
                unsigned int rg[2][2];
#pragma unroll
                for (int tt = 0; tt < 2; tt++) {
                    const int tkv = blk * 2 + tt;
                    float p0 = __builtin_amdgcn_exp2f(sacc[tkv][tq][0]);
                    float p1 = __builtin_amdgcn_exp2f(sacc[tkv][tq][1]);
                    float p2 = __builtin_amdgcn_exp2f(sacc[tkv][tq][2]);
                    float p3 = __builtin_amdgcn_exp2f(sacc[tkv][tq][3]);
                    rg[tt][0] = pkrtz(p0, p1);
                    rg[tt][1] = pkrtz(p2, p3);
                }
                auto ab0 = __builtin_amdgcn_permlane32_swap(rg[0][0], rg[1][0], false, false);
                auto uw0 = __builtin_amdgcn_permlane16_swap(ab0[0], ab0[1], false, false);
                auto ab1 = __builtin_amdgcn_permlane32_swap(rg[0][1], rg[1][1], false, false);
                auto uw1 = __builtin_amdgcn_permlane16_swap(ab1[0], ab1[1], false, false);
                union {
                    unsigned int u[4];
                    f16x8 v;
                } bb;
                bb.u[0] = uw0[0];  // k = q*8+0,1
                bb.u[1] = uw1[0];  // k = q*8+2,3
                bb.u[2] = uw0[1];  // k = q*8+4,5
                bb.u[3] = uw1[1];  // k = q*8+6,7
                bfrag[blk][tq] = bb.v;
            }
        }

#pragma unroll
        for (int blk = 0; blk < 2; blk++) {
#pragma unroll
            for (int td = 0; td < 4; td++) {
                f16x8 va = *(const f16x8*)(vb[blk] + cur * 4096 + td * 1024);
#pragma unroll
                for (int tq = 0; tq < 2; tq++)
                    oacc[td][tq] = MFMA16(va, bfrag[blk][tq], oacc[td][tq]);
            }
#pragma unroll
            for (int tq = 0; tq < 2; tq++)
                oext[tq] = MFMA16(vones, bfrag[blk][tq], oext[tq]);
        }
        __builtin_amdgcn_s_barrier();  // B: cur reads done before t+1 overwrites
    };

    for (int t = 0; t < 32; t += 2) {
        body(0, t);
        body(1, t + 1);
    }

    const int b = bh >> 2, h = bh & 3;
#pragma unroll
    for (int tq = 0; tq < 2; tq++) {
        const float inv = 1.f / oext[tq][0];  // every lane holds full sum for q=l16
        const int q = q0 + tq * 16 + l16;
        const size_t base = ((size_t)(b * 2048 + q)) * 256 + h * 64;
#pragma unroll
        for (int td = 0; td < 4; td++) {
            f16x4 o = {(f16)(oacc[td][tq][0] * inv), (f16)(oacc[td][tq][1] * inv),
                       (f16)(oacc[td][tq][2] * inv), (f16)(oacc[td][tq][3] * inv)};
            *(f16x4*)(Mo + base + td * 16 + quad * 4) = o;
        }
    }
}

// ---------------------------------------------------------------- LN + GELU (wave per row)
__global__ __launch_bounds__(256) void k_ln_gelu(f16* __restrict__ h,
                                                 const float* __restrict__ g,
                                                 const float* __restrict__ bb) {
    const int tid = threadIdx.x, wave = tid >> 6, lane = tid & 63;
    const size_t row = (size_t)blockIdx.x * 4 + wave;
    f16* hr = h + row * 512 + lane * 8;
    f16x8 v = *(const f16x8*)hr;
    float x[8];
    float s = 0.f, sq = 0.f;
#pragma unroll
    for (int i = 0; i < 8; i++) {
        x[i] = (float)v[i];
        s += x[i];
        sq += x[i] * x[i];
    }
#pragma unroll
    for (int off = 1; off < 64; off <<= 1) {
        s += __shfl_xor(s, off);
        sq += __shfl_xor(sq, off);
    }
    const float mu = s * (1.f / 512.f);
    const float var = sq * (1.f / 512.f) - mu * mu;
    const float rstd = rsqrtf(var + 1e-5f);
    float4 g0 = *(const float4*)(g + lane * 8), g1 = *(const float4*)(g + lane * 8 + 4);
    float4 b0 = *(const float4*)(bb + lane * 8), b1 = *(const float4*)(bb + lane * 8 + 4);
    float gg[8] = {g0.x, g0.y, g0.z, g0.w, g1.x, g1.y, g1.z, g1.w};
    float bv[8] = {b0.x, b0.y, b0.z, b0.w, b1.x, b1.y, b1.z, b1.w};
#pragma unroll
    for (int i = 0; i < 8; i++) {
        float a = (x[i] - mu) * rstd * gg[i] + bv[i];
        a = 0.5f * a * (1.f + erff(a * 0.70710678118f));
        v[i] = (f16)a;
    }
    *(f16x8*)hr = v;
}

// ---------------------------------------------------------------- launch

extern "C" void kernel_launch(void* const* d_in, const int* in_sizes, int n_in, void* d_out,
                              int out_size, void* d_ws, size_t ws_size, hipStream_t stream) {
    const float* x0 = (const float*)d_in[0];
    const float* x1 = (const float*)d_in[1];
    const float* Wqk = (const float*)d_in[2];
    const float* bqk = (const float*)d_in[3];
    const float* Wv = (const float*)d_in[4];
    const float* bv = (const float*)d_in[5];
    const float* Wout = (const float*)d_in[6];
    const float* bout = (const float*)d_in[7];
    const float* W1 = (const float*)d_in[8];
    const float* b1 = (const float*)d_in[9];
    const float* lng = (const float*)d_in[10];
    const float* lnb = (const float*)d_in[11];
    const float* W2 = (const float*)d_in[12];
    const float* b2 = (const float*)d_in[13];
    float* out = (float*)d_out;

    char* ws = (char*)d_ws;
    f16* xh = (f16*)(ws);                 // 0..16M   (2,B,L,C) f16
    f16* qk = (f16*)(ws + 16777216);      // 16..32M  (2,B,H,L,D) f16 (scaled)
    f16* vt = (f16*)(ws + 33554432);      // 32..48M  (2,B,H,D,L) f16
    f16* mbuf = (f16*)(ws + 50331648);    // 48..64M  (2,B,L,C) f16 (flash out)
    f16* hbuf = qk;                       // 16..48M  (2,B,L,2C) f16 (qk+vt dead after flash)
    // transient weights in the mbuf region (dead before flash writes mbuf;
    // moved out of the qk region because the piggybacked WoW1b reads them
    // WHILE proj writes qk)
    f16* w1bt = (f16*)(ws + 50331648);    // [512][256] f16
    f16* woutf16 = w1bt + 131072;         // [256][256] f16
    // persistent weights
    f16* wcat_t = (f16*)(ws + 67108864);  // [512][256]
    f16* w1t = wcat_t + 131072;           // [512][512] effective W1
    f16* w2t = w1t + 262144;              // [256][512]
    float* bias_eff = (float*)(w2t + 131072);  // [512] f32

    k_prep<<<11008, 256, 0, stream>>>(x0, x1, Wqk, Wv, W1, W2, Wout, b1, bout, xh, wcat_t, w1t,
                                      w1bt, w2t, woutf16, bias_eff);
    // projections: [x0;x1] @ [Wqk|Wv] -> qk (scaled, head layout) + v^T
    // + piggybacked WoW1b: w1t[:, 256:] = (Wout @ W1_bot)^T on blocks x>=256,y==0
    k_gemm<<<dim3(260, 2), 256, 0, stream>>>(xh, xh, 1 << 30, 256, wcat_t, 256, 512, bqk, bv, 0,
                                             qk, vt, nullptr, w1bt, woutf16, w1t);
    // bidirectional flash attention -> mbuf
    k_flash<<<dim3(32, 16, 2), 256, 0, stream>>>(qk, vt, mbuf);
    // FFN1: [x | attn] @ Weff + bias_eff   (Wout folded in)
    k_gemm<<<dim3(256, 2), 256, 0, stream>>>(xh, mbuf, 256, 256, w1t, 512, 512, bias_eff,
                                             nullptr, 2, hbuf, nullptr, nullptr, nullptr,
                                             nullptr, nullptr);
    k_ln_gelu<<<8192, 256, 0, stream>>>(hbuf, lng, lnb);
    // FFN2 + residual (f16 xh) -> fp32 out, single bn pass
    k_gemm<<<dim3(256, 1), 256, 0, stream>>>(hbuf, hbuf, 1 << 30, 512, w2t, 512, 256, b2,
                                             nullptr, 3, out, nullptr, xh, nullptr, nullptr,
                                             nullptr);
}

// Round 10
// 300.819 us; speedup vs baseline: 1.9365x; 1.9365x over previous
//
#include <hip/hip_runtime.h>
#include <hip/hip_bf16.h>

typedef _Float16 f16;
typedef _Float16 f16x8 __attribute__((ext_vector_type(8)));
typedef _Float16 f16x4 __attribute__((ext_vector_type(4)));
typedef _Float16 f16x2 __attribute__((ext_vector_type(2)));
typedef float f32x4 __attribute__((ext_vector_type(4)));
typedef float f32x2 __attribute__((ext_vector_type(2)));

#define MFMA16(a, b, c) __builtin_amdgcn_mfma_f32_16x16x32_f16((a), (b), (c), 0, 0, 0)

__device__ __forceinline__ void load16(const void* g, void* l) {
    __builtin_amdgcn_global_load_lds((const __attribute__((address_space(1))) void*)g,
                                     (__attribute__((address_space(3))) void*)l, 16, 0, 0);
}

__device__ __forceinline__ unsigned int pkrtz(float a, float b) {
    return __builtin_bit_cast(unsigned int, __builtin_amdgcn_cvt_pkrtz(a, b));
}

// ---------------------------------------------------------------- prep (fused)
// R6 layout (NO Wout-fold here: folding it into prep cost ~35us twice, R5/R7 —
// the 256-iter serial-loop blocks straggle at the tail of the dispatch).
// blocks 0..8191      : x0,x1 fp32 -> xh f16
// blocks 8192..8703   : wcat_t[n][k] = [Wqk^T; Wv^T]
// blocks 8704..9215   : w1t[n][k<256] = W1_top^T
// blocks 9216..9727   : w1bt[n][t] = W1[256+t][n]
// blocks 9728..10239  : w2t[n][k] = W2[k][n]
// blocks 10240..10495 : woutf16 = (f16)Wout
// blocks 10496..11007 : bias_eff[n] = b1[n] + sum_j bout[j]*W1[256+j][n]
__global__ __launch_bounds__(256) void k_prep(const float* __restrict__ x0,
                                              const float* __restrict__ x1,
                                              const float* __restrict__ Wqk,
                                              const float* __restrict__ Wv,
                                              const float* __restrict__ W1,
                                              const float* __restrict__ W2,
                                              const float* __restrict__ Wout,
                                              const float* __restrict__ b1,
                                              const float* __restrict__ bout,
                                              f16* __restrict__ xh, f16* __restrict__ wcat_t,
                                              f16* __restrict__ w1t, f16* __restrict__ w1bt,
                                              f16* __restrict__ w2t, f16* __restrict__ woutf16,
                                              float* __restrict__ bias_eff) {
    __shared__ float red[4];
    const int blk = blockIdx.x, tid = threadIdx.x;
    if (blk < 8192) {
        size_t i = ((size_t)blk * 256 + tid) * 4;
        const float* src = (i < 4194304) ? (x0 + i) : (x1 + (i - 4194304));
        float4 v = *(const float4*)src;
        f16x4 o = {(f16)v.x, (f16)v.y, (f16)v.z, (f16)v.w};
        *(f16x4*)(xh + i) = o;
    } else if (blk < 8704) {
        int n = blk - 8192;
        const float* W = (n < 256) ? Wqk : Wv;
        wcat_t[n * 256 + tid] = (f16)W[tid * 256 + (n & 255)];
    } else if (blk < 9216) {
        int n = blk - 8704;
        w1t[n * 512 + tid] = (f16)W1[tid * 512 + n];
    } else if (blk < 9728) {
        int n = blk - 9216;
        w1bt[n * 256 + tid] = (f16)W1[(256 + tid) * 512 + n];
    } else if (blk < 10240) {
        int j = blk - 9728;
        int n = j >> 1, k = (j & 1) * 256 + tid;
        w2t[n * 512 + k] = (f16)W2[k * 256 + n];
    } else if (blk < 10496) {
        int o = (blk - 10240) * 256 + tid;
        woutf16[o] = (f16)Wout[o];
    } else {
        int n = blk - 10496;
        float s = bout[tid] * W1[(size_t)(256 + tid) * 512 + n];
#pragma unroll
        for (int off = 1; off < 64; off <<= 1) s += __shfl_xor(s, off);
        int wave = tid >> 6, lane = tid & 63;
        if (lane == 0) red[wave] = s;
        __syncthreads();
        if (tid == 0) bias_eff[n] = b1[n] + red[0] + red[1] + red[2] + red[3];
    }
}

// ---------------------------------------------------------------- GEMM, 128m x 256n tile
// C[M][N] = A[M][K] (f16) @ Bt[N][K]^T (f16), fp32 accum. Wide n-tile halves the
// number of bn passes -> halves A re-fetch traffic. Grid x = bm (fast).
// mode 0: proj  -> y==0: (v+bqk)*scale to qk (2,B,H,L,D); y==1: v+bv to vt (2,B,H,D,L)
// mode 2: f16 out [M][N] = v + bias1[n]
// mode 3: f32 out [M][256] = v + bias1[n] + (float)resh[m][n]
// mode 4: f16 out[m][256+n] stride 512, no bias (WoW1b -> w1t right half)
// R12: WoW1b piggyback — when pgOut != nullptr, blocks x>=256 (y==0) run the
// WoW1b GEMM with substituted params; saves its dispatch.
// R15: qk epilogue LDS-transpose — R14's operand swap in the K-loop caused acc
// register spill (VGPR 128, 680MB scratch traffic/dispatch, 170us). The K-loop
// is back to the single ordering; write-amplification is fixed AFTER the loop:
// stage each tm-slice (32 rows x 256 cols) in LDS (Bs free post-loop, stride
// 264 = conflict-free writes + 16B-aligned reads), then store 128B-coalesced
// runs (1x sector amp vs 8x for the direct 8B/lane @128B-stride stores).
__global__ __launch_bounds__(256, 2) void k_gemm(const f16* __restrict__ A1,
                                                 const f16* __restrict__ A2, int ksplit,
                                                 int strideA, const f16* __restrict__ Bt, int K,
                                                 int N, const float* __restrict__ bias1,
                                                 const float* __restrict__ bias2, int mode,
                                                 void* __restrict__ out1, void* __restrict__ out2,
                                                 const f16* __restrict__ resh,
                                                 const f16* __restrict__ pgA,
                                                 const f16* __restrict__ pgBt,
                                                 f16* __restrict__ pgOut) {
    int bm0 = blockIdx.x * 128;
    int bn0 = blockIdx.y * 256;
    if (pgOut != nullptr && blockIdx.x >= 256) {
        if (blockIdx.y != 0) return;
        A1 = pgA;
        A2 = pgA;
        ksplit = 1 << 30;
        strideA = 256;
        Bt = pgBt;
        K = 256;
        N = 256;
        bias1 = nullptr;
        bias2 = nullptr;
        mode = 4;
        out1 = pgOut;
        out2 = nullptr;
        resh = nullptr;
        bm0 = (blockIdx.x - 256) * 128;
        bn0 = 0;
    }
    __shared__ f16 As[2][4096];  // [128 rows][32 k] 16B chunks, chunk ^ (row&3)
    __shared__ f16 Bs[2][8192];  // [256 rows][32 k]
    const int tid = threadIdx.x;
    const int lane = tid & 63, wave = tid >> 6;
    const int quad = lane >> 4, l16 = lane & 15;
    const int wm0 = (wave & 1) * 64, wn0 = (wave >> 1) * 128;
    const int axor = l16 & 3;

    f32x4 acc[4][8];
#pragma unroll
    for (int tm = 0; tm < 4; tm++)
#pragma unroll
        for (int tn = 0; tn < 8; tn++) acc[tm][tn] = (f32x4){0.f, 0.f, 0.f, 0.f};

    auto stage = [&](int buf, int kt) {
        const int k0 = kt * 32;
        const f16* Ab = (k0 < ksplit) ? A1 : A2;
        const int koff = (k0 < ksplit) ? k0 : k0 - ksplit;
#pragma unroll
        for (int rd = 0; rd < 2; rd++) {
            const int cbase = rd * 256 + wave * 64;
            const int c = cbase + lane;
            const int row = c >> 2, col = (c & 3) ^ (row & 3);
            load16(Ab + (size_t)(bm0 + row) * strideA + koff + col * 8, &As[buf][cbase * 8]);
        }
#pragma unroll
        for (int rd = 0; rd < 4; rd++) {
            const int cbase = rd * 256 + wave * 64;
            const int c = cbase + lane;
            const int row = c >> 2, col = (c & 3) ^ (row & 3);
            load16(Bt + (size_t)(bn0 + row) * K + k0 + col * 8, &Bs[buf][cbase * 8]);
        }
    };

    const int NT = K >> 5;
    stage(0, 0);
    __syncthreads();
    for (int kt = 0; kt < NT; kt++) {
        const int cur = kt & 1;
        if (kt + 1 < NT) stage(cur ^ 1, kt + 1);
        f16x8 af[4], bf[8];
#pragma unroll
        for (int t = 0; t < 4; t++)
            af[t] = *(const f16x8*)&As[cur][(wm0 + t * 16 + l16) * 32 + (quad ^ axor) * 8];
#pragma unroll
        for (int t = 0; t < 8; t++)
            bf[t] = *(const f16x8*)&Bs[cur][(wn0 + t * 16 + l16) * 32 + (quad ^ axor) * 8];
#pragma unroll
        for (int tm = 0; tm < 4; tm++)
#pragma unroll
            for (int tn = 0; tn < 8; tn++) acc[tm][tn] = MFMA16(bf[tn], af[tm], acc[tm][tn]);
        __syncthreads();
    }

    if (mode == 0 && bn0 == 0) {
        // qk half: LDS-transpose epilogue for coalesced [l][d] stores.
        // tile[32][264] f16 over Bs (free after last barrier).
        f16* tile = &Bs[0][0];
#pragma unroll
        for (int tm = 0; tm < 4; tm++) {
            const int r = (wave & 1) * 16 + l16;
#pragma unroll
            for (int tn = 0; tn < 8; tn++) {
                const int c = wn0 + tn * 16 + quad * 4;
                float4 bi = *(const float4*)(bias1 + c);
                f32x4 v = acc[tm][tn];
                // scale = D^-0.25 * sqrt(log2(e)) so flash softmax uses exp2
                f16x4 o = {(f16)((v[0] + bi.x) * 0.42466090f),
                           (f16)((v[1] + bi.y) * 0.42466090f),
                           (f16)((v[2] + bi.z) * 0.42466090f),
                           (f16)((v[3] + bi.w) * 0.42466090f)};
                *(f16x4*)&tile[r * 264 + c] = o;
            }
            __syncthreads();
#pragma unroll
            for (int j = 0; j < 4; j++) {
                const int ch = tid + j * 256;
                const int row = ch >> 5, cc = (ch & 31) * 8;
                const int m = bm0 + (row >> 4) * 64 + tm * 16 + (row & 15);
                const int s = m >> 14, r14 = m & 16383, b = r14 >> 11, l = r14 & 2047;
                const int h = cc >> 6, d = cc & 63;
                const size_t hh = (size_t)((s * 8 + b) * 4 + h);
                *(f16x8*)((f16*)out1 + (hh * 2048 + l) * 64 + d) =
                    *(const f16x8*)&tile[row * 264 + cc];
            }
            __syncthreads();
        }
        return;
    }

#pragma unroll
    for (int tm = 0; tm < 4; tm++) {
        const int m = bm0 + wm0 + tm * 16 + l16;
#pragma unroll
        for (int tn = 0; tn < 8; tn++) {
            const int n = bn0 + wn0 + tn * 16 + quad * 4;
            f32x4 v = acc[tm][tn];
            if (mode == 0) {
                // vt half (y==1): n >= 256 always
                const int s = m >> 14, r14 = m & 16383, b = r14 >> 11, l = r14 & 2047;
                const int n2 = n - 256;
                float4 bi = *(const float4*)(bias2 + n2);
                const int h = n2 >> 6, d = n2 & 63;
                const size_t hh = (size_t)((s * 8 + b) * 4 + h);
                f16* o2 = (f16*)out2 + (hh * 64 + d) * 2048 + l;
                o2[0] = (f16)(v[0] + bi.x);
                o2[2048] = (f16)(v[1] + bi.y);
                o2[4096] = (f16)(v[2] + bi.z);
                o2[6144] = (f16)(v[3] + bi.w);
            } else if (mode == 2) {
                float4 bi = *(const float4*)(bias1 + n);
                f16x4 o = {(f16)(v[0] + bi.x), (f16)(v[1] + bi.y), (f16)(v[2] + bi.z),
                           (f16)(v[3] + bi.w)};
                *(f16x4*)((f16*)out1 + (size_t)m * N + n) = o;
            } else if (mode == 3) {
                float4 bi = *(const float4*)(bias1 + n);
                f16x4 rr = *(const f16x4*)(resh + (size_t)m * 256 + n);
                float4 o = {v[0] + bi.x + (float)rr[0], v[1] + bi.y + (float)rr[1],
                            v[2] + bi.z + (float)rr[2], v[3] + bi.w + (float)rr[3]};
                *(float4*)((float*)out1 + (size_t)m * 256 + n) = o;
            } else {  // mode 4
                f16x4 o = {(f16)v[0], (f16)v[1], (f16)v[2], (f16)v[3]};
                *(f16x4*)((f16*)out1 + (size_t)m * 512 + 256 + n) = o;
            }
        }
    }
}

// ---------------------------------------------------------------- flash attention (S^T form)
// S^T = K Q^T. PV uses full-rate K=32 MFMA; B-operand built from adjacent 16-kv
// S^T fragments with permlane32/16 swaps (R8). R9 VALU diet. R11 ones-row MFMA
// row-sum. R13: T4 double-barrier counted-vmcnt (2 raw barriers/body, vmcnt(4),
// no drain in main loop). Unchanged since R13.
// Grid x=bh (fast): all 16 q-tiles of one K/V panel on one XCD -> L2-served.
__global__ __launch_bounds__(256, 4) void k_flash(const f16* __restrict__ qkbuf,
                                                  const f16* __restrict__ vtbuf,
                                                  f16* __restrict__ mbuf) {
    const int z = blockIdx.z;
    const int bh = blockIdx.x;  // b*4+h (fast dim -> XCD-panel affinity)
    const int qt = blockIdx.y;  // 0..15
    const size_t HSZ = 2048 * 64;
    const size_t SSZ = 32 * HSZ;
    const f16* Q = qkbuf + (z ? SSZ : 0) + bh * HSZ;
    const f16* Kp = qkbuf + (z ? 0 : SSZ) + bh * HSZ;
    const f16* Vt = vtbuf + (z ? 0 : SSZ) + bh * HSZ;
    f16* Mo = mbuf + (size_t)z * (16384 * 256);

    __shared__ f16 Ks[2][4096];  // 64 rows x 64 cols, xor-swizzled 16B chunks
    __shared__ f16 Vs[2][4096];  // 64 d-rows x 64 kv-cols, same swizzle

    const int tid = threadIdx.x, lane = tid & 63, wave = tid >> 6;
    const int quad = lane >> 4, l16 = lane & 15;
    const int srow = lane >> 3;
    const int slc = (lane & 7) ^ (srow & 7);
    const int sw = l16 & 7;

    const int q0 = qt * 128 + wave * 32;
    f16x8 qf[2][2];
#pragma unroll
    for (int tq = 0; tq < 2; tq++)
#pragma unroll
        for (int kk = 0; kk < 2; kk++)
            qf[tq][kk] =
                *(const f16x8*)(Q + (size_t)(q0 + tq * 16 + l16) * 64 + kk * 32 + quad * 8);

    // loop-invariant per-lane LDS read bases (elements). Reads add compile-time
    // buf*4096 + tile*1024 -> folded into ds_read offset immediates.
    const f16* kb[2] = {&Ks[0][l16 * 64 + ((0 + quad) ^ sw) * 8],
                        &Ks[0][l16 * 64 + ((4 + quad) ^ sw) * 8]};
    const f16* vb[2] = {&Vs[0][l16 * 64 + ((0 + quad) ^ sw) * 8],
                        &Vs[0][l16 * 64 + ((4 + quad) ^ sw) * 8]};

    // loop-invariant stage pointers (global per-lane src, wave-uniform LDS dst)
    const f16* pK0 = Kp + (size_t)(wave * 16 + srow) * 64 + slc * 8;
    const f16* pK1 = pK0 + 8 * 64;
    const f16* pV0 = Vt + (size_t)(wave * 16 + srow) * 2048 + slc * 8;
    const f16* pV1 = pV0 + 8 * 2048;
    f16* kd0 = &Ks[0][(wave * 2 + 0) * 512];
    f16* kd1 = &Ks[0][(wave * 2 + 1) * 512];
    f16* vd0 = &Vs[0][(wave * 2 + 0) * 512];
    f16* vd1 = &Vs[0][(wave * 2 + 1) * 512];

    auto stage = [&](int buf, int kv0) {
        load16(pK0 + (size_t)kv0 * 64, kd0 + buf * 4096);
        load16(pK1 + (size_t)kv0 * 64, kd1 + buf * 4096);
        load16(pV0 + kv0, vd0 + buf * 4096);
        load16(pV1 + kv0, vd1 + buf * 4096);
    };

    f32x4 oacc[4][2];
#pragma unroll
    for (int td = 0; td < 4; td++)
#pragma unroll
        for (int tq = 0; tq < 2; tq++) oacc[td][tq] = (f32x4){0.f, 0.f, 0.f, 0.f};
    f32x4 oext[2] = {{0.f, 0.f, 0.f, 0.f}, {0.f, 0.f, 0.f, 0.f}};  // ones-row l-sum
    const f16x8 vones = {(f16)1.f, (f16)1.f, (f16)1.f, (f16)1.f,
                         (f16)1.f, (f16)1.f, (f16)1.f, (f16)1.f};

    stage(0, 0);

    auto body = [&](int cur, int t) {
        if (t < 31) {
            stage(cur ^ 1, (t + 1) * 64);
            asm volatile("s_waitcnt vmcnt(4)" ::: "memory");  // cur's loads landed
        } else {
            asm volatile("s_waitcnt vmcnt(0)" ::: "memory");
        }
        __builtin_amdgcn_s_barrier();  // A: all waves' cur loads landed

        f32x4 sacc[4][2];
#pragma unroll
        for (int tkv = 0; tkv < 4; tkv++)
#pragma unroll
            for (int tq = 0; tq < 2; tq++)
                sacc[tkv][tq] = (f32x4){-8.f, -8.f, -8.f, -8.f};  // folds exp2(s-8)
#pragma unroll
        for (int kk = 0; kk < 2; kk++) {
#pragma unroll
            for (int tkv = 0; tkv < 4; tkv++) {
                f16x8 ka = *(const f16x8*)(kb[kk] + cur * 4096 + tkv * 1024);
#pragma unroll
                for (int tq = 0; tq < 2; tq++)
                    sacc[tkv][tq] = MFMA16(ka, qf[tq][kk], sacc[tkv][tq]);
            }
        }

        // P = exp2(sacc); pack to f16 (rtz); repack 16-kv pairs to K=32 B-frags
        f16x8 bfrag[2][2];  // [32-kv block][tq]
#pragma unroll
        for (int blk = 0; blk < 2; blk++) {
#pragma unroll
            for (int tq = 0; tq < 2; tq++) {
                unsigned int rg[2][2];
#pragma unroll
                for (int tt = 0; tt < 2; tt++) {
                    const int tkv = blk * 2 + tt;
                    float p0 = __builtin_amdgcn_exp2f(sacc[tkv][tq][0]);
                    float p1 = __builtin_amdgcn_exp2f(sacc[tkv][tq][1]);
                    float p2 = __builtin_amdgcn_exp2f(sacc[tkv][tq][2]);
                    float p3 = __builtin_amdgcn_exp2f(sacc[tkv][tq][3]);
                    rg[tt][0] = pkrtz(p0, p1);
                    rg[tt][1] = pkrtz(p2, p3);
                }
                auto ab0 = __builtin_amdgcn_permlane32_swap(rg[0][0], rg[1][0], false, false);
                auto uw0 = __builtin_amdgcn_permlane16_swap(ab0[0], ab0[1], false, false);
                auto ab1 = __builtin_amdgcn_permlane32_swap(rg[0][1], rg[1][1], false, false);
                auto uw1 = __builtin_amdgcn_permlane16_swap(ab1[0], ab1[1], false, false);
                union {
                    unsigned int u[4];
                    f16x8 v;
                } bb;
                bb.u[0] = uw0[0];  // k = q*8+0,1
                bb.u[1] = uw1[0];  // k = q*8+2,3
                bb.u[2] = uw0[1];  // k = q*8+4,5
                bb.u[3] = uw1[1];  // k = q*8+6,7
                bfrag[blk][tq] = bb.v;
            }
        }

#pragma unroll
        for (int blk = 0; blk < 2; blk++) {
#pragma unroll
            for (int td = 0; td < 4; td++) {
                f16x8 va = *(const f16x8*)(vb[blk] + cur * 4096 + td * 1024);
#pragma unroll
                for (int tq = 0; tq < 2; tq++)
                    oacc[td][tq] = MFMA16(va, bfrag[blk][tq], oacc[td][tq]);
            }
#pragma unroll
            for (int tq = 0; tq < 2; tq++)
                oext[tq] = MFMA16(vones, bfrag[blk][tq], oext[tq]);
        }
        __builtin_amdgcn_s_barrier();  // B: cur reads done before t+1 overwrites
    };

    for (int t = 0; t < 32; t += 2) {
        body(0, t);
        body(1, t + 1);
    }

    const int b = bh >> 2, h = bh & 3;
#pragma unroll
    for (int tq = 0; tq < 2; tq++) {
        const float inv = 1.f / oext[tq][0];  // every lane holds full sum for q=l16
        const int q = q0 + tq * 16 + l16;
        const size_t base = ((size_t)(b * 2048 + q)) * 256 + h * 64;
#pragma unroll
        for (int td = 0; td < 4; td++) {
            f16x4 o = {(f16)(oacc[td][tq][0] * inv), (f16)(oacc[td][tq][1] * inv),
                       (f16)(oacc[td][tq][2] * inv), (f16)(oacc[td][tq][3] * inv)};
            *(f16x4*)(Mo + base + td * 16 + quad * 4) = o;
        }
    }
}

// ---------------------------------------------------------------- LN + GELU (wave per row)
__global__ __launch_bounds__(256) void k_ln_gelu(f16* __restrict__ h,
                                                 const float* __restrict__ g,
                                                 const float* __restrict__ bb) {
    const int tid = threadIdx.x, wave = tid >> 6, lane = tid & 63;
    const size_t row = (size_t)blockIdx.x * 4 + wave;
    f16* hr = h + row * 512 + lane * 8;
    f16x8 v = *(const f16x8*)hr;
    float x[8];
    float s = 0.f, sq = 0.f;
#pragma unroll
    for (int i = 0; i < 8; i++) {
        x[i] = (float)v[i];
        s += x[i];
        sq += x[i] * x[i];
    }
#pragma unroll
    for (int off = 1; off < 64; off <<= 1) {
        s += __shfl_xor(s, off);
        sq += __shfl_xor(sq, off);
    }
    const float mu = s * (1.f / 512.f);
    const float var = sq * (1.f / 512.f) - mu * mu;
    const float rstd = rsqrtf(var + 1e-5f);
    float4 g0 = *(const float4*)(g + lane * 8), g1 = *(const float4*)(g + lane * 8 + 4);
    float4 b0 = *(const float4*)(bb + lane * 8), b1 = *(const float4*)(bb + lane * 8 + 4);
    float gg[8] = {g0.x, g0.y, g0.z, g0.w, g1.x, g1.y, g1.z, g1.w};
    float bv[8] = {b0.x, b0.y, b0.z, b0.w, b1.x, b1.y, b1.z, b1.w};
#pragma unroll
    for (int i = 0; i < 8; i++) {
        float a = (x[i] - mu) * rstd * gg[i] + bv[i];
        a = 0.5f * a * (1.f + erff(a * 0.70710678118f));
        v[i] = (f16)a;
    }
    *(f16x8*)hr = v;
}

// ---------------------------------------------------------------- launch

extern "C" void kernel_launch(void* const* d_in, const int* in_sizes, int n_in, void* d_out,
                              int out_size, void* d_ws, size_t ws_size, hipStream_t stream) {
    const float* x0 = (const float*)d_in[0];
    const float* x1 = (const float*)d_in[1];
    const float* Wqk = (const float*)d_in[2];
    const float* bqk = (const float*)d_in[3];
    const float* Wv = (const float*)d_in[4];
    const float* bv = (const float*)d_in[5];
    const float* Wout = (const float*)d_in[6];
    const float* bout = (const float*)d_in[7];
    const float* W1 = (const float*)d_in[8];
    const float* b1 = (const float*)d_in[9];
    const float* lng = (const float*)d_in[10];
    const float* lnb = (const float*)d_in[11];
    const float* W2 = (const float*)d_in[12];
    const float* b2 = (const float*)d_in[13];
    float* out = (float*)d_out;

    char* ws = (char*)d_ws;
    f16* xh = (f16*)(ws);                 // 0..16M   (2,B,L,C) f16
    f16* qk = (f16*)(ws + 16777216);      // 16..32M  (2,B,H,L,D) f16 (scaled)
    f16* vt = (f16*)(ws + 33554432);      // 32..48M  (2,B,H,D,L) f16
    f16* mbuf = (f16*)(ws + 50331648);    // 48..64M  (2,B,L,C) f16 (flash out)
    f16* hbuf = qk;                       // 16..48M  (2,B,L,2C) f16 (qk+vt dead after flash)
    // transient weights in the mbuf region (dead before flash writes mbuf;
    // moved out of the qk region because the piggybacked WoW1b reads them
    // WHILE proj writes qk)
    f16* w1bt = (f16*)(ws + 50331648);    // [512][256] f16
    f16* woutf16 = w1bt + 131072;         // [256][256] f16
    // persistent weights
    f16* wcat_t = (f16*)(ws + 67108864);  // [512][256]
    f16* w1t = wcat_t + 131072;           // [512][512] effective W1
    f16* w2t = w1t + 262144;              // [256][512]
    float* bias_eff = (float*)(w2t + 131072);  // [512] f32

    k_prep<<<11008, 256, 0, stream>>>(x0, x1, Wqk, Wv, W1, W2, Wout, b1, bout, xh, wcat_t, w1t,
                                      w1bt, w2t, woutf16, bias_eff);
    // projections: [x0;x1] @ [Wqk|Wv] -> qk (scaled, head layout) + v^T
    // + piggybacked WoW1b: w1t[:, 256:] = (Wout @ W1_bot)^T on blocks x>=256,y==0
    k_gemm<<<dim3(260, 2), 256, 0, stream>>>(xh, xh, 1 << 30, 256, wcat_t, 256, 512, bqk, bv, 0,
                                             qk, vt, nullptr, w1bt, woutf16, w1t);
    // bidirectional flash attention -> mbuf
    k_flash<<<dim3(32, 16, 2), 256, 0, stream>>>(qk, vt, mbuf);
    // FFN1: [x | attn] @ Weff + bias_eff   (Wout folded in)
    k_gemm<<<dim3(256, 2), 256, 0, stream>>>(xh, mbuf, 256, 256, w1t, 512, 512, bias_eff,
                                             nullptr, 2, hbuf, nullptr, nullptr, nullptr,
                                             nullptr, nullptr);
    k_ln_gelu<<<8192, 256, 0, stream>>>(hbuf, lng, lnb);
    // FFN2 + residual (f16 xh) -> fp32 out, single bn pass
    k_gemm<<<dim3(256, 1), 256, 0, stream>>>(hbuf, hbuf, 1 << 30, 512, w2t, 512, 256, b2,
                                             nullptr, 3, out, nullptr, xh, nullptr, nullptr,
                                             nullptr);
}

// Round 11
// 296.284 us; speedup vs baseline: 1.9661x; 1.0153x over previous
//
#include <hip/hip_runtime.h>
#include <hip/hip_bf16.h>

typedef _Float16 f16;
typedef _Float16 f16x8 __attribute__((ext_vector_type(8)));
typedef _Float16 f16x4 __attribute__((ext_vector_type(4)));
typedef _Float16 f16x2 __attribute__((ext_vector_type(2)));
typedef float f32x4 __attribute__((ext_vector_type(4)));
typedef float f32x2 __attribute__((ext_vector_type(2)));

#define MFMA16(a, b, c) __builtin_amdgcn_mfma_f32_16x16x32_f16((a), (b), (c), 0, 0, 0)

__device__ __forceinline__ void load16(const void* g, void* l) {
    __builtin_amdgcn_global_load_lds((const __attribute__((address_space(1))) void*)g,
                                     (__attribute__((address_space(3))) void*)l, 16, 0, 0);
}

__device__ __forceinline__ unsigned int pkrtz(float a, float b) {
    return __builtin_bit_cast(unsigned int, __builtin_amdgcn_cvt_pkrtz(a, b));
}

// ---------------------------------------------------------------- prep (fused)
// R6 layout (NO Wout-fold here: folding it into prep cost ~35us twice, R5/R7 —
// the 256-iter serial-loop blocks straggle at the tail of the dispatch).
// blocks 0..8191      : x0,x1 fp32 -> xh f16
// blocks 8192..8703   : wcat_t[n][k] = [Wqk^T; Wv^T]
// blocks 8704..9215   : w1t[n][k<256] = W1_top^T
// blocks 9216..9727   : w1bt[n][t] = W1[256+t][n]
// blocks 9728..10239  : w2t[n][k] = W2[k][n]
// blocks 10240..10495 : woutf16 = (f16)Wout
// blocks 10496..11007 : bias_eff[n] = b1[n] + sum_j bout[j]*W1[256+j][n]
__global__ __launch_bounds__(256) void k_prep(const float* __restrict__ x0,
                                              const float* __restrict__ x1,
                                              const float* __restrict__ Wqk,
                                              const float* __restrict__ Wv,
                                              const float* __restrict__ W1,
                                              const float* __restrict__ W2,
                                              const float* __restrict__ Wout,
                                              const float* __restrict__ b1,
                                              const float* __restrict__ bout,
                                              f16* __restrict__ xh, f16* __restrict__ wcat_t,
                                              f16* __restrict__ w1t, f16* __restrict__ w1bt,
                                              f16* __restrict__ w2t, f16* __restrict__ woutf16,
                                              float* __restrict__ bias_eff) {
    __shared__ float red[4];
    const int blk = blockIdx.x, tid = threadIdx.x;
    if (blk < 8192) {
        size_t i = ((size_t)blk * 256 + tid) * 4;
        const float* src = (i < 4194304) ? (x0 + i) : (x1 + (i - 4194304));
        float4 v = *(const float4*)src;
        f16x4 o = {(f16)v.x, (f16)v.y, (f16)v.z, (f16)v.w};
        *(f16x4*)(xh + i) = o;
    } else if (blk < 8704) {
        int n = blk - 8192;
        const float* W = (n < 256) ? Wqk : Wv;
        wcat_t[n * 256 + tid] = (f16)W[tid * 256 + (n & 255)];
    } else if (blk < 9216) {
        int n = blk - 8704;
        w1t[n * 512 + tid] = (f16)W1[tid * 512 + n];
    } else if (blk < 9728) {
        int n = blk - 9216;
        w1bt[n * 256 + tid] = (f16)W1[(256 + tid) * 512 + n];
    } else if (blk < 10240) {
        int j = blk - 9728;
        int n = j >> 1, k = (j & 1) * 256 + tid;
        w2t[n * 512 + k] = (f16)W2[k * 256 + n];
    } else if (blk < 10496) {
        int o = (blk - 10240) * 256 + tid;
        woutf16[o] = (f16)Wout[o];
    } else {
        int n = blk - 10496;
        float s = bout[tid] * W1[(size_t)(256 + tid) * 512 + n];
#pragma unroll
        for (int off = 1; off < 64; off <<= 1) s += __shfl_xor(s, off);
        int wave = tid >> 6, lane = tid & 63;
        if (lane == 0) red[wave] = s;
        __syncthreads();
        if (tid == 0) bias_eff[n] = b1[n] + red[0] + red[1] + red[2] + red[3];
    }
}

// ---------------------------------------------------------------- GEMM, 128m x 256n tile
// C[M][N] = A[M][K] (f16) @ Bt[N][K]^T (f16), fp32 accum. Grid x = bm (fast).
// mode 0: proj  -> y==0: (v+bqk)*scale to qk (2,B,H,L,D); y==1: v+bv to vt (2,B,H,D,L)
// mode 2: f16 out [M][N] = v + bias1[n]            (staged epilogue, R16)
// mode 3: f32 out [M][256] = v + bias1[n] + resh   (staged epilogue, R16)
// mode 4: f16 out[m][256+n] stride 512, no bias (WoW1b -> w1t right half)
// R12: WoW1b piggyback on blocks x>=256 (y==0).
// R15: qk epilogue LDS-transpose (1x write sectors).
// R16: (a) T4 counted-vmcnt double-barrier K-loop (pattern proven in flash R13;
// at 2 blocks/CU the per-kt vmcnt(0) drain has little TLP to hide it);
// (b) mode 2 staged epilogue — direct stores were 8B/lane @1024B stride = 8x
// sector amp on 33.5MB; staged rows give 512B-contiguous runs (1x);
// (c) mode 3 staged f32 epilogue — 4x write amp -> 1x, and the resh residual
// read (was 8B/lane @1024B = 8x) becomes coalesced.
__global__ __launch_bounds__(256, 2) void k_gemm(const f16* __restrict__ A1,
                                                 const f16* __restrict__ A2, int ksplit,
                                                 int strideA, const f16* __restrict__ Bt, int K,
                                                 int N, const float* __restrict__ bias1,
                                                 const float* __restrict__ bias2, int mode,
                                                 void* __restrict__ out1, void* __restrict__ out2,
                                                 const f16* __restrict__ resh,
                                                 const f16* __restrict__ pgA,
                                                 const f16* __restrict__ pgBt,
                                                 f16* __restrict__ pgOut) {
    int bm0 = blockIdx.x * 128;
    int bn0 = blockIdx.y * 256;
    if (pgOut != nullptr && blockIdx.x >= 256) {
        if (blockIdx.y != 0) return;
        A1 = pgA;
        A2 = pgA;
        ksplit = 1 << 30;
        strideA = 256;
        Bt = pgBt;
        K = 256;
        N = 256;
        bias1 = nullptr;
        bias2 = nullptr;
        mode = 4;
        out1 = pgOut;
        out2 = nullptr;
        resh = nullptr;
        bm0 = (blockIdx.x - 256) * 128;
        bn0 = 0;
    }
    __shared__ f16 As[2][4096];  // [128 rows][32 k] 16B chunks, chunk ^ (row&3)
    __shared__ f16 Bs[2][8192];  // [256 rows][32 k]
    const int tid = threadIdx.x;
    const int lane = tid & 63, wave = tid >> 6;
    const int quad = lane >> 4, l16 = lane & 15;
    const int wm0 = (wave & 1) * 64, wn0 = (wave >> 1) * 128;
    const int axor = l16 & 3;

    f32x4 acc[4][8];
#pragma unroll
    for (int tm = 0; tm < 4; tm++)
#pragma unroll
        for (int tn = 0; tn < 8; tn++) acc[tm][tn] = (f32x4){0.f, 0.f, 0.f, 0.f};

    auto stage = [&](int buf, int kt) {
        const int k0 = kt * 32;
        const f16* Ab = (k0 < ksplit) ? A1 : A2;
        const int koff = (k0 < ksplit) ? k0 : k0 - ksplit;
#pragma unroll
        for (int rd = 0; rd < 2; rd++) {
            const int cbase = rd * 256 + wave * 64;
            const int c = cbase + lane;
            const int row = c >> 2, col = (c & 3) ^ (row & 3);
            load16(Ab + (size_t)(bm0 + row) * strideA + koff + col * 8, &As[buf][cbase * 8]);
        }
#pragma unroll
        for (int rd = 0; rd < 4; rd++) {
            const int cbase = rd * 256 + wave * 64;
            const int c = cbase + lane;
            const int row = c >> 2, col = (c & 3) ^ (row & 3);
            load16(Bt + (size_t)(bn0 + row) * K + k0 + col * 8, &Bs[buf][cbase * 8]);
        }
    };

    const int NT = K >> 5;
    stage(0, 0);
    for (int kt = 0; kt < NT; kt++) {
        const int cur = kt & 1;
        if (kt + 1 < NT) {
            stage(cur ^ 1, kt + 1);
            asm volatile("s_waitcnt vmcnt(6)" ::: "memory");  // cur's 6 loads landed
        } else {
            asm volatile("s_waitcnt vmcnt(0)" ::: "memory");
        }
        __builtin_amdgcn_s_barrier();  // A: all waves' cur loads landed
        f16x8 af[4], bf[8];
#pragma unroll
        for (int t = 0; t < 4; t++)
            af[t] = *(const f16x8*)&As[cur][(wm0 + t * 16 + l16) * 32 + (quad ^ axor) * 8];
#pragma unroll
        for (int t = 0; t < 8; t++)
            bf[t] = *(const f16x8*)&Bs[cur][(wn0 + t * 16 + l16) * 32 + (quad ^ axor) * 8];
#pragma unroll
        for (int tm = 0; tm < 4; tm++)
#pragma unroll
            for (int tn = 0; tn < 8; tn++) acc[tm][tn] = MFMA16(bf[tn], af[tm], acc[tm][tn]);
        __builtin_amdgcn_s_barrier();  // B: cur reads done before next stage
    }

    if (mode == 0 && bn0 == 0) {
        // qk half: LDS-transpose epilogue for coalesced [l][d] stores.
        f16* tile = &Bs[0][0];  // 32 x 264
#pragma unroll
        for (int tm = 0; tm < 4; tm++) {
            const int r = (wave & 1) * 16 + l16;
#pragma unroll
            for (int tn = 0; tn < 8; tn++) {
                const int c = wn0 + tn * 16 + quad * 4;
                float4 bi = *(const float4*)(bias1 + c);
                f32x4 v = acc[tm][tn];
                // scale = D^-0.25 * sqrt(log2(e)) so flash softmax uses exp2
                f16x4 o = {(f16)((v[0] + bi.x) * 0.42466090f),
                           (f16)((v[1] + bi.y) * 0.42466090f),
                           (f16)((v[2] + bi.z) * 0.42466090f),
                           (f16)((v[3] + bi.w) * 0.42466090f)};
                *(f16x4*)&tile[r * 264 + c] = o;
            }
            __syncthreads();
#pragma unroll
            for (int j = 0; j < 4; j++) {
                const int ch = tid + j * 256;
                const int row = ch >> 5, cc = (ch & 31) * 8;
                const int m = bm0 + (row >> 4) * 64 + tm * 16 + (row & 15);
                const int s = m >> 14, r14 = m & 16383, b = r14 >> 11, l = r14 & 2047;
                const int h = cc >> 6, d = cc & 63;
                const size_t hh = (size_t)((s * 8 + b) * 4 + h);
                *(f16x8*)((f16*)out1 + (hh * 2048 + l) * 64 + d) =
                    *(const f16x8*)&tile[row * 264 + cc];
            }
            __syncthreads();
        }
        return;
    }

    if (mode == 2) {
        // staged epilogue: rows of 256 f16 (512B) contiguous -> 1x sector amp
        f16* tile = &Bs[0][0];  // 32 x 264
#pragma unroll
        for (int tm = 0; tm < 4; tm++) {
            const int r = (wave & 1) * 16 + l16;
#pragma unroll
            for (int tn = 0; tn < 8; tn++) {
                const int c = wn0 + tn * 16 + quad * 4;
                float4 bi = *(const float4*)(bias1 + bn0 + c);
                f32x4 v = acc[tm][tn];
                f16x4 o = {(f16)(v[0] + bi.x), (f16)(v[1] + bi.y), (f16)(v[2] + bi.z),
                           (f16)(v[3] + bi.w)};
                *(f16x4*)&tile[r * 264 + c] = o;
            }
            __syncthreads();
#pragma unroll
            for (int j = 0; j < 4; j++) {
                const int ch = tid + j * 256;
                const int row = ch >> 5, cc = (ch & 31) * 8;
                const int m = bm0 + (row >> 4) * 64 + tm * 16 + (row & 15);
                *(f16x8*)((f16*)out1 + (size_t)m * N + bn0 + cc) =
                    *(const f16x8*)&tile[row * 264 + cc];
            }
            __syncthreads();
        }
        return;
    }

    if (mode == 3) {
        // staged f32 epilogue (16-row chunks) + coalesced resh residual read
        float* t32 = (float*)&Bs[0][0];  // 16 x 264 f32 (16.9KB <= 32KB Bs)
#pragma unroll
        for (int tm = 0; tm < 4; tm++) {
#pragma unroll
            for (int half = 0; half < 2; half++) {
                if ((wave & 1) == half) {
#pragma unroll
                    for (int tn = 0; tn < 8; tn++) {
                        const int c = wn0 + tn * 16 + quad * 4;
                        float4 bi = *(const float4*)(bias1 + c);
                        f32x4 v = acc[tm][tn];
                        float4 o = {v[0] + bi.x, v[1] + bi.y, v[2] + bi.z, v[3] + bi.w};
                        *(float4*)&t32[l16 * 264 + c] = o;
                    }
                }
                __syncthreads();
#pragma unroll
                for (int j = 0; j < 4; j++) {
                    const int ch = tid + j * 256;
                    const int row = ch >> 6, cc = (ch & 63) * 4;
                    const int m = bm0 + half * 64 + tm * 16 + row;
                    f16x4 rr = *(const f16x4*)(resh + (size_t)m * 256 + cc);
                    const float* ts = &t32[row * 264 + cc];
                    float4 o = {ts[0] + (float)rr[0], ts[1] + (float)rr[1],
                                ts[2] + (float)rr[2], ts[3] + (float)rr[3]};
                    *(float4*)((float*)out1 + (size_t)m * 256 + cc) = o;
                }
                __syncthreads();
            }
        }
        return;
    }

#pragma unroll
    for (int tm = 0; tm < 4; tm++) {
        const int m = bm0 + wm0 + tm * 16 + l16;
#pragma unroll
        for (int tn = 0; tn < 8; tn++) {
            const int n = bn0 + wn0 + tn * 16 + quad * 4;
            f32x4 v = acc[tm][tn];
            if (mode == 0) {
                // vt half (y==1): n >= 256 always; 32B runs (2x amp, acceptable)
                const int s = m >> 14, r14 = m & 16383, b = r14 >> 11, l = r14 & 2047;
                const int n2 = n - 256;
                float4 bi = *(const float4*)(bias2 + n2);
                const int h = n2 >> 6, d = n2 & 63;
                const size_t hh = (size_t)((s * 8 + b) * 4 + h);
                f16* o2 = (f16*)out2 + (hh * 64 + d) * 2048 + l;
                o2[0] = (f16)(v[0] + bi.x);
                o2[2048] = (f16)(v[1] + bi.y);
                o2[4096] = (f16)(v[2] + bi.z);
                o2[6144] = (f16)(v[3] + bi.w);
            } else {  // mode 4
                f16x4 o = {(f16)v[0], (f16)v[1], (f16)v[2], (f16)v[3]};
                *(f16x4*)((f16*)out1 + (size_t)m * 512 + 256 + n) = o;
            }
        }
    }
}

// ---------------------------------------------------------------- flash attention (S^T form)
// S^T = K Q^T. PV uses full-rate K=32 MFMA; B-operand built from adjacent 16-kv
// S^T fragments with permlane32/16 swaps (R8). R9 VALU diet. R11 ones-row MFMA
// row-sum. R13: T4 double-barrier counted-vmcnt (2 raw barriers/body, vmcnt(4),
// no drain in main loop). Unchanged since R13.
// Grid x=bh (fast): all 16 q-tiles of one K/V panel on one XCD -> L2-served.
__global__ __launch_bounds__(256, 4) void k_flash(const f16* __restrict__ qkbuf,
                                                  const f16* __restrict__ vtbuf,
                                                  f16* __restrict__ mbuf) {
    const int z = blockIdx.z;
    const int bh = blockIdx.x;  // b*4+h (fast dim -> XCD-panel affinity)
    const int qt = blockIdx.y;  // 0..15
    const size_t HSZ = 2048 * 64;
    const size_t SSZ = 32 * HSZ;
    const f16* Q = qkbuf + (z ? SSZ : 0) + bh * HSZ;
    const f16* Kp = qkbuf + (z ? 0 : SSZ) + bh * HSZ;
    const f16* Vt = vtbuf + (z ? 0 : SSZ) + bh * HSZ;
    f16* Mo = mbuf + (size_t)z * (16384 * 256);

    __shared__ f16 Ks[2][4096];  // 64 rows x 64 cols, xor-swizzled 16B chunks
    __shared__ f16 Vs[2][4096];  // 64 d-rows x 64 kv-cols, same swizzle

    const int tid = threadIdx.x, lane = tid & 63, wave = tid >> 6;
    const int quad = lane >> 4, l16 = lane & 15;
    const int srow = lane >> 3;
    const int slc = (lane & 7) ^ (srow & 7);
    const int sw = l16 & 7;

    const int q0 = qt * 128 + wave * 32;
    f16x8 qf[2][2];
#pragma unroll
    for (int tq = 0; tq < 2; tq++)
#pragma unroll
        for (int kk = 0; kk < 2; kk++)
            qf[tq][kk] =
                *(const f16x8*)(Q + (size_t)(q0 + tq * 16 + l16) * 64 + kk * 32 + quad * 8);

    // loop-invariant per-lane LDS read bases (elements). Reads add compile-time
    // buf*4096 + tile*1024 -> folded into ds_read offset immediates.
    const f16* kb[2] = {&Ks[0][l16 * 64 + ((0 + quad) ^ sw) * 8],
                        &Ks[0][l16 * 64 + ((4 + quad) ^ sw) * 8]};
    const f16* vb[2] = {&Vs[0][l16 * 64 + ((0 + quad) ^ sw) * 8],
                        &Vs[0][l16 * 64 + ((4 + quad) ^ sw) * 8]};

    // loop-invariant stage pointers (global per-lane src, wave-uniform LDS dst)
    const f16* pK0 = Kp + (size_t)(wave * 16 + srow) * 64 + slc * 8;
    const f16* pK1 = pK0 + 8 * 64;
    const f16* pV0 = Vt + (size_t)(wave * 16 + srow) * 2048 + slc * 8;
    const f16* pV1 = pV0 + 8 * 2048;
    f16* kd0 = &Ks[0][(wave * 2 + 0) * 512];
    f16* kd1 = &Ks[0][(wave * 2 + 1) * 512];
    f16* vd0 = &Vs[0][(wave * 2 + 0) * 512];
    f16* vd1 = &Vs[0][(wave * 2 + 1) * 512];

    auto stage = [&](int buf, int kv0) {
        load16(pK0 + (size_t)kv0 * 64, kd0 + buf * 4096);
        load16(pK1 + (size_t)kv0 * 64, kd1 + buf * 4096);
        load16(pV0 + kv0, vd0 + buf * 4096);
        load16(pV1 + kv0, vd1 + buf * 4096);
    };

    f32x4 oacc[4][2];
#pragma unroll
    for (int td = 0; td < 4; td++)
#pragma unroll
        for (int tq = 0; tq < 2; tq++) oacc[td][tq] = (f32x4){0.f, 0.f, 0.f, 0.f};
    f32x4 oext[2] = {{0.f, 0.f, 0.f, 0.f}, {0.f, 0.f, 0.f, 0.f}};  // ones-row l-sum
    const f16x8 vones = {(f16)1.f, (f16)1.f, (f16)1.f, (f16)1.f,
                         (f16)1.f, (f16)1.f, (f16)1.f, (f16)1.f};

    stage(0, 0);

    auto body = [&](int cur, int t) {
        if (t < 31) {
            stage(cur ^ 1, (t + 1) * 64);
            asm volatile("s_waitcnt vmcnt(4)" ::: "memory");  // cur's loads landed
        } else {
            asm volatile("s_waitcnt vmcnt(0)" ::: "memory");
        }
        __builtin_amdgcn_s_barrier();  // A: all waves' cur loads landed

        f32x4 sacc[4][2];
#pragma unroll
        for (int tkv = 0; tkv < 4; tkv++)
#pragma unroll
            for (int tq = 0; tq < 2; tq++)
                sacc[tkv][tq] = (f32x4){-8.f, -8.f, -8.f, -8.f};  // folds exp2(s-8)
#pragma unroll
        for (int kk = 0; kk < 2; kk++) {
#pragma unroll
            for (int tkv = 0; tkv < 4; tkv++) {
                f16x8 ka = *(const f16x8*)(kb[kk] + cur * 4096 + tkv * 1024);
#pragma unroll
                for (int tq = 0; tq < 2; tq++)
                    sacc[tkv][tq] = MFMA16(ka, qf[tq][kk], sacc[tkv][tq]);
            }
        }

        // P = exp2(sacc); pack to f16 (rtz); repack 16-kv pairs to K=32 B-frags
        f16x8 bfrag[2][2];  // [32-kv block][tq]
#pragma unroll
        for (int blk = 0; blk < 2; blk++) {
#pragma unroll
            for (int tq = 0; tq < 2; tq++) {
                unsigned int rg[2][2];
#pragma unroll
                for (int tt = 0; tt < 2; tt++) {
                    const int tkv = blk * 2 + tt;
                    float p0 = __builtin_amdgcn_exp2f(sacc[tkv][tq][0]);
                    float p1 = __builtin_amdgcn_exp2f(sacc[tkv][tq][1]);
                    float p2 = __builtin_amdgcn_exp2f(sacc[tkv][tq][2]);
                    float p3 = __builtin_amdgcn_exp2f(sacc[tkv][tq][3]);
                    rg[tt][0] = pkrtz(p0, p1);
                    rg[tt][1] = pkrtz(p2, p3);
                }
                auto ab0 = __builtin_amdgcn_permlane32_swap(rg[0][0], rg[1][0], false, false);
                auto uw0 = __builtin_amdgcn_permlane16_swap(ab0[0], ab0[1], false, false);
                auto ab1 = __builtin_amdgcn_permlane32_swap(rg[0][1], rg[1][1], false, false);
                auto uw1 = __builtin_amdgcn_permlane16_swap(ab1[0], ab1[1], false, false);
                union {
                    unsigned int u[4];
                    f16x8 v;
                } bb;
                bb.u[0] = uw0[0];  // k = q*8+0,1
                bb.u[1] = uw1[0];  // k = q*8+2,3
                bb.u[2] = uw0[1];  // k = q*8+4,5
                bb.u[3] = uw1[1];  // k = q*8+6,7
                bfrag[blk][tq] = bb.v;
            }
        }

#pragma unroll
        for (int blk = 0; blk < 2; blk++) {
#pragma unroll
            for (int td = 0; td < 4; td++) {
                f16x8 va = *(const f16x8*)(vb[blk] + cur * 4096 + td * 1024);
#pragma unroll
                for (int tq = 0; tq < 2; tq++)
                    oacc[td][tq] = MFMA16(va, bfrag[blk][tq], oacc[td][tq]);
            }
#pragma unroll
            for (int tq = 0; tq < 2; tq++)
                oext[tq] = MFMA16(vones, bfrag[blk][tq], oext[tq]);
        }
        __builtin_amdgcn_s_barrier();  // B: cur reads done before t+1 overwrites
    };

    for (int t = 0; t < 32; t += 2) {
        body(0, t);
        body(1, t + 1);
    }

    const int b = bh >> 2, h = bh & 3;
#pragma unroll
    for (int tq = 0; tq < 2; tq++) {
        const float inv = 1.f / oext[tq][0];  // every lane holds full sum for q=l16
        const int q = q0 + tq * 16 + l16;
        const size_t base = ((size_t)(b * 2048 + q)) * 256 + h * 64;
#pragma unroll
        for (int td = 0; td < 4; td++) {
            f16x4 o = {(f16)(oacc[td][tq][0] * inv), (f16)(oacc[td][tq][1] * inv),
                       (f16)(oacc[td][tq][2] * inv), (f16)(oacc[td][tq][3] * inv)};
            *(f16x4*)(Mo + base + td * 16 + quad * 4) = o;
        }
    }
}

// ---------------------------------------------------------------- LN + GELU (wave per row)
__global__ __launch_bounds__(256) void k_ln_gelu(f16* __restrict__ h,
                                                 const float* __restrict__ g,
                                                 const float* __restrict__ bb) {
    const int tid = threadIdx.x, wave = tid >> 6, lane = tid & 63;
    const size_t row = (size_t)blockIdx.x * 4 + wave;
    f16* hr = h + row * 512 + lane * 8;
    f16x8 v = *(const f16x8*)hr;
    float x[8];
    float s = 0.f, sq = 0.f;
#pragma unroll
    for (int i = 0; i < 8; i++) {
        x[i] = (float)v[i];
        s += x[i];
        sq += x[i] * x[i];
    }
#pragma unroll
    for (int off = 1; off < 64; off <<= 1) {
        s += __shfl_xor(s, off);
        sq += __shfl_xor(sq, off);
    }
    const float mu = s * (1.f / 512.f);
    const float var = sq * (1.f / 512.f) - mu * mu;
    const float rstd = rsqrtf(var + 1e-5f);
    float4 g0 = *(const float4*)(g + lane * 8), g1 = *(const float4*)(g + lane * 8 + 4);
    float4 b0 = *(const float4*)(bb + lane * 8), b1 = *(const float4*)(bb + lane * 8 + 4);
    float gg[8] = {g0.x, g0.y, g0.z, g0.w, g1.x, g1.y, g1.z, g1.w};
    float bv[8] = {b0.x, b0.y, b0.z, b0.w, b1.x, b1.y, b1.z, b1.w};
#pragma unroll
    for (int i = 0; i < 8; i++) {
        float a = (x[i] - mu) * rstd * gg[i] + bv[i];
        a = 0.5f * a * (1.f + erff(a * 0.70710678118f));
        v[i] = (f16)a;
    }
    *(f16x8*)hr = v;
}

// ---------------------------------------------------------------- launch

extern "C" void kernel_launch(void* const* d_in, const int* in_sizes, int n_in, void* d_out,
                              int out_size, void* d_ws, size_t ws_size, hipStream_t stream) {
    const float* x0 = (const float*)d_in[0];
    const float* x1 = (const float*)d_in[1];
    const float* Wqk = (const float*)d_in[2];
    const float* bqk = (const float*)d_in[3];
    const float* Wv = (const float*)d_in[4];
    const float* bv = (const float*)d_in[5];
    const float* Wout = (const float*)d_in[6];
    const float* bout = (const float*)d_in[7];
    const float* W1 = (const float*)d_in[8];
    const float* b1 = (const float*)d_in[9];
    const float* lng = (const float*)d_in[10];
    const float* lnb = (const float*)d_in[11];
    const float* W2 = (const float*)d_in[12];
    const float* b2 = (const float*)d_in[13];
    float* out = (float*)d_out;

    char* ws = (char*)d_ws;
    f16* xh = (f16*)(ws);                 // 0..16M   (2,B,L,C) f16
    f16* qk = (f16*)(ws + 16777216);      // 16..32M  (2,B,H,L,D) f16 (scaled)
    f16* vt = (f16*)(ws + 33554432);      // 32..48M  (2,B,H,D,L) f16
    f16* mbuf = (f16*)(ws + 50331648);    // 48..64M  (2,B,L,C) f16 (flash out)
    f16* hbuf = qk;                       // 16..48M  (2,B,L,2C) f16 (qk+vt dead after flash)
    // transient weights in the mbuf region (dead before flash writes mbuf;
    // moved out of the qk region because the piggybacked WoW1b reads them
    // WHILE proj writes qk)
    f16* w1bt = (f16*)(ws + 50331648);    // [512][256] f16
    f16* woutf16 = w1bt + 131072;         // [256][256] f16
    // persistent weights
    f16* wcat_t = (f16*)(ws + 67108864);  // [512][256]
    f16* w1t = wcat_t + 131072;           // [512][512] effective W1
    f16* w2t = w1t + 262144;              // [256][512]
    float* bias_eff = (float*)(w2t + 131072);  // [512] f32

    k_prep<<<11008, 256, 0, stream>>>(x0, x1, Wqk, Wv, W1, W2, Wout, b1, bout, xh, wcat_t, w1t,
                                      w1bt, w2t, woutf16, bias_eff);
    // projections: [x0;x1] @ [Wqk|Wv] -> qk (scaled, head layout) + v^T
    // + piggybacked WoW1b: w1t[:, 256:] = (Wout @ W1_bot)^T on blocks x>=256,y==0
    k_gemm<<<dim3(260, 2), 256, 0, stream>>>(xh, xh, 1 << 30, 256, wcat_t, 256, 512, bqk, bv, 0,
                                             qk, vt, nullptr, w1bt, woutf16, w1t);
    // bidirectional flash attention -> mbuf
    k_flash<<<dim3(32, 16, 2), 256, 0, stream>>>(qk, vt, mbuf);
    // FFN1: [x | attn] @ Weff + bias_eff   (Wout folded in)
    k_gemm<<<dim3(256, 2), 256, 0, stream>>>(xh, mbuf, 256, 256, w1t, 512, 512, bias_eff,
                                             nullptr, 2, hbuf, nullptr, nullptr, nullptr,
                                             nullptr, nullptr);
    k_ln_gelu<<<8192, 256, 0, stream>>>(hbuf, lng, lnb);
    // FFN2 + residual (f16 xh) -> fp32 out, single bn pass
    k_gemm<<<dim3(256, 1), 256, 0, stream>>>(hbuf, hbuf, 1 << 30, 512, w2t, 512, 256, b2,
                                             nullptr, 3, out, nullptr, xh, nullptr, nullptr,
                                             nullptr);
}

// Round 12
// 282.952 us; speedup vs baseline: 2.0588x; 1.0471x over previous
//
#include <hip/hip_runtime.h>
#include <hip/hip_bf16.h>

typedef _Float16 f16;
typedef _Float16 f16x8 __attribute__((ext_vector_type(8)));
typedef _Float16 f16x4 __attribute__((ext_vector_type(4)));
typedef _Float16 f16x2 __attribute__((ext_vector_type(2)));
typedef float f32x4 __attribute__((ext_vector_type(4)));

#define MFMA16(a, b, c) __builtin_amdgcn_mfma_f32_16x16x32_f16((a), (b), (c), 0, 0, 0)

__device__ __forceinline__ void load16(const void* g, void* l) {
    __builtin_amdgcn_global_load_lds((const __attribute__((address_space(1))) void*)g,
                                     (__attribute__((address_space(3))) void*)l, 16, 0, 0);
}

__device__ __forceinline__ unsigned int pkrtz(float a, float b) {
    return __builtin_bit_cast(unsigned int, __builtin_amdgcn_cvt_pkrtz(a, b));
}

// ---------------------------------------------------------------- prep (fused)
// R6 layout (NO Wout-fold here: folding it into prep cost ~35us twice, R5/R7 —
// the 256-iter serial-loop blocks straggle at the tail of the dispatch).
// blocks 0..8191      : x0,x1 fp32 -> xh f16
// blocks 8192..8703   : wcat_t[n][k] = [Wqk^T; Wv^T]
// blocks 8704..9215   : w1t[n][k<256] = W1_top^T
// blocks 9216..9727   : w1bt[n][t] = W1[256+t][n]
// blocks 9728..10239  : w2t[n][k] = W2[k][n]
// blocks 10240..10495 : woutf16 = (f16)Wout
// blocks 10496..11007 : bias_eff[n] = b1[n] + sum_j bout[j]*W1[256+j][n]
__global__ __launch_bounds__(256) void k_prep(const float* __restrict__ x0,
                                              const float* __restrict__ x1,
                                              const float* __restrict__ Wqk,
                                              const float* __restrict__ Wv,
                                              const float* __restrict__ W1,
                                              const float* __restrict__ W2,
                                              const float* __restrict__ Wout,
                                              const float* __restrict__ b1,
                                              const float* __restrict__ bout,
                                              f16* __restrict__ xh, f16* __restrict__ wcat_t,
                                              f16* __restrict__ w1t, f16* __restrict__ w1bt,
                                              f16* __restrict__ w2t, f16* __restrict__ woutf16,
                                              float* __restrict__ bias_eff) {
    __shared__ float red[4];
    const int blk = blockIdx.x, tid = threadIdx.x;
    if (blk < 8192) {
        size_t i = ((size_t)blk * 256 + tid) * 4;
        const float* src = (i < 4194304) ? (x0 + i) : (x1 + (i - 4194304));
        float4 v = *(const float4*)src;
        f16x4 o = {(f16)v.x, (f16)v.y, (f16)v.z, (f16)v.w};
        *(f16x4*)(xh + i) = o;
    } else if (blk < 8704) {
        int n = blk - 8192;
        const float* W = (n < 256) ? Wqk : Wv;
        wcat_t[n * 256 + tid] = (f16)W[tid * 256 + (n & 255)];
    } else if (blk < 9216) {
        int n = blk - 8704;
        w1t[n * 512 + tid] = (f16)W1[tid * 512 + n];
    } else if (blk < 9728) {
        int n = blk - 9216;
        w1bt[n * 256 + tid] = (f16)W1[(256 + tid) * 512 + n];
    } else if (blk < 10240) {
        int j = blk - 9728;
        int n = j >> 1, k = (j & 1) * 256 + tid;
        w2t[n * 512 + k] = (f16)W2[k * 256 + n];
    } else if (blk < 10496) {
        int o = (blk - 10240) * 256 + tid;
        woutf16[o] = (f16)Wout[o];
    } else {
        int n = blk - 10496;
        float s = bout[tid] * W1[(size_t)(256 + tid) * 512 + n];
#pragma unroll
        for (int off = 1; off < 64; off <<= 1) s += __shfl_xor(s, off);
        int wave = tid >> 6, lane = tid & 63;
        if (lane == 0) red[wave] = s;
        __syncthreads();
        if (tid == 0) bias_eff[n] = b1[n] + red[0] + red[1] + red[2] + red[3];
    }
}

// ---------------------------------------------------------------- GEMM, TMm x 256n tile
// C[M][N] = A[M][K] (f16) @ Bt[N][K]^T (f16), fp32 accum. Grid x = bm (fast).
// mode 0: proj  -> y==0: (v+bqk)*scale to qk (2,B,H,L,D); y==1: v+bv to vt (2,B,H,D,L)
// mode 2: f16 out [M][N] = v + bias1[n]            (staged epilogue, R16)
// mode 3: f32 out [M][256] = v + bias1[n] + resh   (staged epilogue, R16)
// mode 4: f16 out[m][256+n] stride 512, no bias (WoW1b -> w1t right half)
// R12: WoW1b piggyback on blocks x>=256 (y==0), TM=128 only.
// R15/R16: staged epilogues (1x write sectors), T4 counted-vmcnt K-loop.
// R17: template TM (128 proj / 64 FFN1+FFN2) — TM=64 halves acc VGPR + LDS so
// FFN1 runs 4 blocks/CU and FFN2 2 blocks/CU (was 1: grid 256 = 1/CU,
// latency-starved at 4 waves/CU).
template <int TM>
__global__ __launch_bounds__(256, 2) void k_gemm(const f16* __restrict__ A1,
                                                 const f16* __restrict__ A2, int ksplit,
                                                 int strideA, const f16* __restrict__ Bt, int K,
                                                 int N, const float* __restrict__ bias1,
                                                 const float* __restrict__ bias2, int mode,
                                                 void* __restrict__ out1, void* __restrict__ out2,
                                                 const f16* __restrict__ resh,
                                                 const f16* __restrict__ pgA,
                                                 const f16* __restrict__ pgBt,
                                                 f16* __restrict__ pgOut) {
    constexpr int WM = TM / 2;    // rows per wave-pair group
    constexpr int TMI = WM / 16;  // tm fragment count
    constexpr int ARD = TM / 64;  // A stage iterations
    int bm0 = blockIdx.x * TM;
    int bn0 = blockIdx.y * 256;
    if constexpr (TM == 128) {
        if (pgOut != nullptr && blockIdx.x >= 256) {
            if (blockIdx.y != 0) return;
            A1 = pgA;
            A2 = pgA;
            ksplit = 1 << 30;
            strideA = 256;
            Bt = pgBt;
            K = 256;
            N = 256;
            bias1 = nullptr;
            bias2 = nullptr;
            mode = 4;
            out1 = pgOut;
            out2 = nullptr;
            resh = nullptr;
            bm0 = (blockIdx.x - 256) * 128;
            bn0 = 0;
        }
    }
    __shared__ f16 As[2][TM * 32];  // [TM rows][32 k] 16B chunks, chunk ^ (row&3)
    __shared__ f16 Bs[2][8192];     // [256 rows][32 k]
    const int tid = threadIdx.x;
    const int lane = tid & 63, wave = tid >> 6;
    const int quad = lane >> 4, l16 = lane & 15;
    const int wm0 = (wave & 1) * WM, wn0 = (wave >> 1) * 128;
    const int axor = l16 & 3;

    f32x4 acc[TMI][8];
#pragma unroll
    for (int tm = 0; tm < TMI; tm++)
#pragma unroll
        for (int tn = 0; tn < 8; tn++) acc[tm][tn] = (f32x4){0.f, 0.f, 0.f, 0.f};

    auto stage = [&](int buf, int kt) {
        const int k0 = kt * 32;
        const f16* Ab = (k0 < ksplit) ? A1 : A2;
        const int koff = (k0 < ksplit) ? k0 : k0 - ksplit;
#pragma unroll
        for (int rd = 0; rd < ARD; rd++) {
            const int cbase = rd * 256 + wave * 64;
            const int c = cbase + lane;
            const int row = c >> 2, col = (c & 3) ^ (row & 3);
            load16(Ab + (size_t)(bm0 + row) * strideA + koff + col * 8, &As[buf][cbase * 8]);
        }
#pragma unroll
        for (int rd = 0; rd < 4; rd++) {
            const int cbase = rd * 256 + wave * 64;
            const int c = cbase + lane;
            const int row = c >> 2, col = (c & 3) ^ (row & 3);
            load16(Bt + (size_t)(bn0 + row) * K + k0 + col * 8, &Bs[buf][cbase * 8]);
        }
    };

    const int NT = K >> 5;
    stage(0, 0);
    for (int kt = 0; kt < NT; kt++) {
        const int cur = kt & 1;
        if (kt + 1 < NT) {
            stage(cur ^ 1, kt + 1);
            if constexpr (TM == 128)
                asm volatile("s_waitcnt vmcnt(6)" ::: "memory");  // cur's 6 loads landed
            else
                asm volatile("s_waitcnt vmcnt(5)" ::: "memory");  // cur's 5 loads landed
        } else {
            asm volatile("s_waitcnt vmcnt(0)" ::: "memory");
        }
        __builtin_amdgcn_s_barrier();  // A: all waves' cur loads landed
        f16x8 af[TMI], bf[8];
#pragma unroll
        for (int t = 0; t < TMI; t++)
            af[t] = *(const f16x8*)&As[cur][(wm0 + t * 16 + l16) * 32 + (quad ^ axor) * 8];
#pragma unroll
        for (int t = 0; t < 8; t++)
            bf[t] = *(const f16x8*)&Bs[cur][(wn0 + t * 16 + l16) * 32 + (quad ^ axor) * 8];
#pragma unroll
        for (int tm = 0; tm < TMI; tm++)
#pragma unroll
            for (int tn = 0; tn < 8; tn++) acc[tm][tn] = MFMA16(bf[tn], af[tm], acc[tm][tn]);
        __builtin_amdgcn_s_barrier();  // B: cur reads done before next stage
    }

    if constexpr (TM == 128) {
        if (mode == 0 && bn0 == 0) {
            // qk half: LDS-transpose epilogue for coalesced [l][d] stores.
            f16* tile = &Bs[0][0];  // 32 x 264
#pragma unroll
            for (int tm = 0; tm < TMI; tm++) {
                const int r = (wave & 1) * 16 + l16;
#pragma unroll
                for (int tn = 0; tn < 8; tn++) {
                    const int c = wn0 + tn * 16 + quad * 4;
                    float4 bi = *(const float4*)(bias1 + c);
                    f32x4 v = acc[tm][tn];
                    // scale = D^-0.25 * sqrt(log2(e)) so flash softmax uses exp2
                    f16x4 o = {(f16)((v[0] + bi.x) * 0.42466090f),
                               (f16)((v[1] + bi.y) * 0.42466090f),
                               (f16)((v[2] + bi.z) * 0.42466090f),
                               (f16)((v[3] + bi.w) * 0.42466090f)};
                    *(f16x4*)&tile[r * 264 + c] = o;
                }
                __syncthreads();
#pragma unroll
                for (int j = 0; j < 4; j++) {
                    const int ch = tid + j * 256;
                    const int row = ch >> 5, cc = (ch & 31) * 8;
                    const int m = bm0 + (row >> 4) * WM + tm * 16 + (row & 15);
                    const int s = m >> 14, r14 = m & 16383, b = r14 >> 11, l = r14 & 2047;
                    const int h = cc >> 6, d = cc & 63;
                    const size_t hh = (size_t)((s * 8 + b) * 4 + h);
                    *(f16x8*)((f16*)out1 + (hh * 2048 + l) * 64 + d) =
                        *(const f16x8*)&tile[row * 264 + cc];
                }
                __syncthreads();
            }
            return;
        }
    }

    if (mode == 2) {
        // staged epilogue: rows of 256 f16 (512B) contiguous -> 1x sector amp
        f16* tile = &Bs[0][0];  // 32 x 264
#pragma unroll
        for (int tm = 0; tm < TMI; tm++) {
            const int r = (wave & 1) * 16 + l16;
#pragma unroll
            for (int tn = 0; tn < 8; tn++) {
                const int c = wn0 + tn * 16 + quad * 4;
                float4 bi = *(const float4*)(bias1 + bn0 + c);
                f32x4 v = acc[tm][tn];
                f16x4 o = {(f16)(v[0] + bi.x), (f16)(v[1] + bi.y), (f16)(v[2] + bi.z),
                           (f16)(v[3] + bi.w)};
                *(f16x4*)&tile[r * 264 + c] = o;
            }
            __syncthreads();
#pragma unroll
            for (int j = 0; j < 4; j++) {
                const int ch = tid + j * 256;
                const int row = ch >> 5, cc = (ch & 31) * 8;
                const int m = bm0 + (row >> 4) * WM + tm * 16 + (row & 15);
                *(f16x8*)((f16*)out1 + (size_t)m * N + bn0 + cc) =
                    *(const f16x8*)&tile[row * 264 + cc];
            }
            __syncthreads();
        }
        return;
    }

    if (mode == 3) {
        // staged f32 epilogue (16-row chunks) + coalesced resh residual read
        float* t32 = (float*)&Bs[0][0];  // 16 x 264 f32
#pragma unroll
        for (int tm = 0; tm < TMI; tm++) {
#pragma unroll
            for (int half = 0; half < 2; half++) {
                if ((wave & 1) == half) {
#pragma unroll
                    for (int tn = 0; tn < 8; tn++) {
                        const int c = wn0 + tn * 16 + quad * 4;
                        float4 bi = *(const float4*)(bias1 + c);
                        f32x4 v = acc[tm][tn];
                        float4 o = {v[0] + bi.x, v[1] + bi.y, v[2] + bi.z, v[3] + bi.w};
                        *(float4*)&t32[l16 * 264 + c] = o;
                    }
                }
                __syncthreads();
#pragma unroll
                for (int j = 0; j < 4; j++) {
                    const int ch = tid + j * 256;
                    const int row = ch >> 6, cc = (ch & 63) * 4;
                    const int m = bm0 + half * WM + tm * 16 + row;
                    f16x4 rr = *(const f16x4*)(resh + (size_t)m * 256 + cc);
                    const float* ts = &t32[row * 264 + cc];
                    float4 o = {ts[0] + (float)rr[0], ts[1] + (float)rr[1],
                                ts[2] + (float)rr[2], ts[3] + (float)rr[3]};
                    *(float4*)((float*)out1 + (size_t)m * 256 + cc) = o;
                }
                __syncthreads();
            }
        }
        return;
    }

    if constexpr (TM == 128) {
#pragma unroll
        for (int tm = 0; tm < TMI; tm++) {
            const int m = bm0 + wm0 + tm * 16 + l16;
#pragma unroll
            for (int tn = 0; tn < 8; tn++) {
                const int n = bn0 + wn0 + tn * 16 + quad * 4;
                f32x4 v = acc[tm][tn];
                if (mode == 0) {
                    // vt half (y==1): n >= 256 always; 32B runs (2x amp, acceptable)
                    const int s = m >> 14, r14 = m & 16383, b = r14 >> 11, l = r14 & 2047;
                    const int n2 = n - 256;
                    float4 bi = *(const float4*)(bias2 + n2);
                    const int h = n2 >> 6, d = n2 & 63;
                    const size_t hh = (size_t)((s * 8 + b) * 4 + h);
                    f16* o2 = (f16*)out2 + (hh * 64 + d) * 2048 + l;
                    o2[0] = (f16)(v[0] + bi.x);
                    o2[2048] = (f16)(v[1] + bi.y);
                    o2[4096] = (f16)(v[2] + bi.z);
                    o2[6144] = (f16)(v[3] + bi.w);
                } else {  // mode 4
                    f16x4 o = {(f16)v[0], (f16)v[1], (f16)v[2], (f16)v[3]};
                    *(f16x4*)((f16*)out1 + (size_t)m * 512 + 256 + n) = o;
                }
            }
        }
    }
}

// ---------------------------------------------------------------- flash attention (S^T form)
// S^T = K Q^T. PV uses full-rate K=32 MFMA; B-operand built from adjacent 16-kv
// S^T fragments with permlane32/16 swaps (R8). R9 VALU diet. R11 ones-row MFMA
// row-sum. R13: T4 double-barrier counted-vmcnt. R17: exp2 fixed shift folded
// into the kk==0 MFMA C-operand (kills 32 v_mov inits/body) — isolated retest
// of one R10-bundle member; if WRITE_SIZE balloons again this was the culprit.
// Grid x=bh (fast): all 16 q-tiles of one K/V panel on one XCD -> L2-served.
__global__ __launch_bounds__(256, 4) void k_flash(const f16* __restrict__ qkbuf,
                                                  const f16* __restrict__ vtbuf,
                                                  f16* __restrict__ mbuf) {
    const int z = blockIdx.z;
    const int bh = blockIdx.x;  // b*4+h (fast dim -> XCD-panel affinity)
    const int qt = blockIdx.y;  // 0..15
    const size_t HSZ = 2048 * 64;
    const size_t SSZ = 32 * HSZ;
    const f16* Q = qkbuf + (z ? SSZ : 0) + bh * HSZ;
    const f16* Kp = qkbuf + (z ? 0 : SSZ) + bh * HSZ;
    const f16* Vt = vtbuf + (z ? 0 : SSZ) + bh * HSZ;
    f16* Mo = mbuf + (size_t)z * (16384 * 256);

    __shared__ f16 Ks[2][4096];  // 64 rows x 64 cols, xor-swizzled 16B chunks
    __shared__ f16 Vs[2][4096];  // 64 d-rows x 64 kv-cols, same swizzle

    const int tid = threadIdx.x, lane = tid & 63, wave = tid >> 6;
    const int quad = lane >> 4, l16 = lane & 15;
    const int srow = lane >> 3;
    const int slc = (lane & 7) ^ (srow & 7);
    const int sw = l16 & 7;

    const int q0 = qt * 128 + wave * 32;
    f16x8 qf[2][2];
#pragma unroll
    for (int tq = 0; tq < 2; tq++)
#pragma unroll
        for (int kk = 0; kk < 2; kk++)
            qf[tq][kk] =
                *(const f16x8*)(Q + (size_t)(q0 + tq * 16 + l16) * 64 + kk * 32 + quad * 8);

    // loop-invariant per-lane LDS read bases (elements). Reads add compile-time
    // buf*4096 + tile*1024 -> folded into ds_read offset immediates.
    const f16* kb[2] = {&Ks[0][l16 * 64 + ((0 + quad) ^ sw) * 8],
                        &Ks[0][l16 * 64 + ((4 + quad) ^ sw) * 8]};
    const f16* vb[2] = {&Vs[0][l16 * 64 + ((0 + quad) ^ sw) * 8],
                        &Vs[0][l16 * 64 + ((4 + quad) ^ sw) * 8]};

    // loop-invariant stage pointers (global per-lane src, wave-uniform LDS dst)
    const f16* pK0 = Kp + (size_t)(wave * 16 + srow) * 64 + slc * 8;
    const f16* pK1 = pK0 + 8 * 64;
    const f16* pV0 = Vt + (size_t)(wave * 16 + srow) * 2048 + slc * 8;
    const f16* pV1 = pV0 + 8 * 2048;
    f16* kd0 = &Ks[0][(wave * 2 + 0) * 512];
    f16* kd1 = &Ks[0][(wave * 2 + 1) * 512];
    f16* vd0 = &Vs[0][(wave * 2 + 0) * 512];
    f16* vd1 = &Vs[0][(wave * 2 + 1) * 512];

    auto stage = [&](int buf, int kv0) {
        load16(pK0 + (size_t)kv0 * 64, kd0 + buf * 4096);
        load16(pK1 + (size_t)kv0 * 64, kd1 + buf * 4096);
        load16(pV0 + kv0, vd0 + buf * 4096);
        load16(pV1 + kv0, vd1 + buf * 4096);
    };

    f32x4 oacc[4][2];
#pragma unroll
    for (int td = 0; td < 4; td++)
#pragma unroll
        for (int tq = 0; tq < 2; tq++) oacc[td][tq] = (f32x4){0.f, 0.f, 0.f, 0.f};
    f32x4 oext[2] = {{0.f, 0.f, 0.f, 0.f}, {0.f, 0.f, 0.f, 0.f}};  // ones-row l-sum
    const f16x8 vones = {(f16)1.f, (f16)1.f, (f16)1.f, (f16)1.f,
                         (f16)1.f, (f16)1.f, (f16)1.f, (f16)1.f};
    const f32x4 nbias = {-8.f, -8.f, -8.f, -8.f};  // exp2 fixed shift as MFMA C-in

    stage(0, 0);

    auto body = [&](int cur, int t) {
        if (t < 31) {
            stage(cur ^ 1, (t + 1) * 64);
            asm volatile("s_waitcnt vmcnt(4)" ::: "memory");  // cur's loads landed
        } else {
            asm volatile("s_waitcnt vmcnt(0)" ::: "memory");
        }
        __builtin_amdgcn_s_barrier();  // A: all waves' cur loads landed

        f32x4 sacc[4][2];
#pragma unroll
        for (int kk = 0; kk < 2; kk++) {
#pragma unroll
            for (int tkv = 0; tkv < 4; tkv++) {
                f16x8 ka = *(const f16x8*)(kb[kk] + cur * 4096 + tkv * 1024);
#pragma unroll
                for (int tq = 0; tq < 2; tq++)
                    sacc[tkv][tq] = MFMA16(ka, qf[tq][kk], kk == 0 ? nbias : sacc[tkv][tq]);
            }
        }

        // P = exp2(sacc); pack to f16 (rtz); repack 16-kv pairs to K=32 B-frags
        f16x8 bfrag[2][2];  // [32-kv block][tq]
#pragma unroll
        for (int blk = 0; blk < 2; blk++) {
#pragma unroll
            for (int tq = 0; tq < 2; tq++) {
                unsigned int rg[2][2];
#pragma unroll
                for (int tt = 0; tt < 2; tt++) {
                    const int tkv = blk * 2 + tt;
                    float p0 = __builtin_amdgcn_exp2f(sacc[tkv][tq][0]);
                    float p1 = __builtin_amdgcn_exp2f(sacc[tkv][tq][1]);
                    float p2 = __builtin_amdgcn_exp2f(sacc[tkv][tq][2]);
                    float p3 = __builtin_amdgcn_exp2f(sacc[tkv][tq][3]);
                    rg[tt][0] = pkrtz(p0, p1);
                    rg[tt][1] = pkrtz(p2, p3);
                }
                auto ab0 = __builtin_amdgcn_permlane32_swap(rg[0][0], rg[1][0], false, false);
                auto uw0 = __builtin_amdgcn_permlane16_swap(ab0[0], ab0[1], false, false);
                auto ab1 = __builtin_amdgcn_permlane32_swap(rg[0][1], rg[1][1], false, false);
                auto uw1 = __builtin_amdgcn_permlane16_swap(ab1[0], ab1[1], false, false);
                union {
                    unsigned int u[4];
                    f16x8 v;
                } bb;
                bb.u[0] = uw0[0];  // k = q*8+0,1
                bb.u[1] = uw1[0];  // k = q*8+2,3
                bb.u[2] = uw0[1];  // k = q*8+4,5
                bb.u[3] = uw1[1];  // k = q*8+6,7
                bfrag[blk][tq] = bb.v;
            }
        }

#pragma unroll
        for (int blk = 0; blk < 2; blk++) {
#pragma unroll
            for (int td = 0; td < 4; td++) {
                f16x8 va = *(const f16x8*)(vb[blk] + cur * 4096 + td * 1024);
#pragma unroll
                for (int tq = 0; tq < 2; tq++)
                    oacc[td][tq] = MFMA16(va, bfrag[blk][tq], oacc[td][tq]);
            }
#pragma unroll
            for (int tq = 0; tq < 2; tq++)
                oext[tq] = MFMA16(vones, bfrag[blk][tq], oext[tq]);
        }
        __builtin_amdgcn_s_barrier();  // B: cur reads done before t+1 overwrites
    };

    for (int t = 0; t < 32; t += 2) {
        body(0, t);
        body(1, t + 1);
    }

    const int b = bh >> 2, h = bh & 3;
#pragma unroll
    for (int tq = 0; tq < 2; tq++) {
        const float inv = 1.f / oext[tq][0];  // every lane holds full sum for q=l16
        const int q = q0 + tq * 16 + l16;
        const size_t base = ((size_t)(b * 2048 + q)) * 256 + h * 64;
#pragma unroll
        for (int td = 0; td < 4; td++) {
            f16x4 o = {(f16)(oacc[td][tq][0] * inv), (f16)(oacc[td][tq][1] * inv),
                       (f16)(oacc[td][tq][2] * inv), (f16)(oacc[td][tq][3] * inv)};
            *(f16x4*)(Mo + base + td * 16 + quad * 4) = o;
        }
    }
}

// ---------------------------------------------------------------- LN + GELU (wave per row)
__global__ __launch_bounds__(256) void k_ln_gelu(f16* __restrict__ h,
                                                 const float* __restrict__ g,
                                                 const float* __restrict__ bb) {
    const int tid = threadIdx.x, wave = tid >> 6, lane = tid & 63;
    const size_t row = (size_t)blockIdx.x * 4 + wave;
    f16* hr = h + row * 512 + lane * 8;
    f16x8 v = *(const f16x8*)hr;
    float x[8];
    float s = 0.f, sq = 0.f;
#pragma unroll
    for (int i = 0; i < 8; i++) {
        x[i] = (float)v[i];
        s += x[i];
        sq += x[i] * x[i];
    }
#pragma unroll
    for (int off = 1; off < 64; off <<= 1) {
        s += __shfl_xor(s, off);
        sq += __shfl_xor(sq, off);
    }
    const float mu = s * (1.f / 512.f);
    const float var = sq * (1.f / 512.f) - mu * mu;
    const float rstd = rsqrtf(var + 1e-5f);
    float4 g0 = *(const float4*)(g + lane * 8), g1 = *(const float4*)(g + lane * 8 + 4);
    float4 b0 = *(const float4*)(bb + lane * 8), b1 = *(const float4*)(bb + lane * 8 + 4);
    float gg[8] = {g0.x, g0.y, g0.z, g0.w, g1.x, g1.y, g1.z, g1.w};
    float bv[8] = {b0.x, b0.y, b0.z, b0.w, b1.x, b1.y, b1.z, b1.w};
#pragma unroll
    for (int i = 0; i < 8; i++) {
        float a = (x[i] - mu) * rstd * gg[i] + bv[i];
        a = 0.5f * a * (1.f + erff(a * 0.70710678118f));
        v[i] = (f16)a;
    }
    *(f16x8*)hr = v;
}

// ---------------------------------------------------------------- launch

extern "C" void kernel_launch(void* const* d_in, const int* in_sizes, int n_in, void* d_out,
                              int out_size, void* d_ws, size_t ws_size, hipStream_t stream) {
    const float* x0 = (const float*)d_in[0];
    const float* x1 = (const float*)d_in[1];
    const float* Wqk = (const float*)d_in[2];
    const float* bqk = (const float*)d_in[3];
    const float* Wv = (const float*)d_in[4];
    const float* bv = (const float*)d_in[5];
    const float* Wout = (const float*)d_in[6];
    const float* bout = (const float*)d_in[7];
    const float* W1 = (const float*)d_in[8];
    const float* b1 = (const float*)d_in[9];
    const float* lng = (const float*)d_in[10];
    const float* lnb = (const float*)d_in[11];
    const float* W2 = (const float*)d_in[12];
    const float* b2 = (const float*)d_in[13];
    float* out = (float*)d_out;

    char* ws = (char*)d_ws;
    f16* xh = (f16*)(ws);                 // 0..16M   (2,B,L,C) f16
    f16* qk = (f16*)(ws + 16777216);      // 16..32M  (2,B,H,L,D) f16 (scaled)
    f16* vt = (f16*)(ws + 33554432);      // 32..48M  (2,B,H,D,L) f16
    f16* mbuf = (f16*)(ws + 50331648);    // 48..64M  (2,B,L,C) f16 (flash out)
    f16* hbuf = qk;                       // 16..48M  (2,B,L,2C) f16 (qk+vt dead after flash)
    // transient weights in the mbuf region (dead before flash writes mbuf;
    // moved out of the qk region because the piggybacked WoW1b reads them
    // WHILE proj writes qk)
    f16* w1bt = (f16*)(ws + 50331648);    // [512][256] f16
    f16* woutf16 = w1bt + 131072;         // [256][256] f16
    // persistent weights
    f16* wcat_t = (f16*)(ws + 67108864);  // [512][256]
    f16* w1t = wcat_t + 131072;           // [512][512] effective W1
    f16* w2t = w1t + 262144;              // [256][512]
    float* bias_eff = (float*)(w2t + 131072);  // [512] f32

    k_prep<<<11008, 256, 0, stream>>>(x0, x1, Wqk, Wv, W1, W2, Wout, b1, bout, xh, wcat_t, w1t,
                                      w1bt, w2t, woutf16, bias_eff);
    // projections: [x0;x1] @ [Wqk|Wv] -> qk (scaled, head layout) + v^T
    // + piggybacked WoW1b: w1t[:, 256:] = (Wout @ W1_bot)^T on blocks x>=256,y==0
    k_gemm<128><<<dim3(260, 2), 256, 0, stream>>>(xh, xh, 1 << 30, 256, wcat_t, 256, 512, bqk,
                                                  bv, 0, qk, vt, nullptr, w1bt, woutf16, w1t);
    // bidirectional flash attention -> mbuf
    k_flash<<<dim3(32, 16, 2), 256, 0, stream>>>(qk, vt, mbuf);
    // FFN1: [x | attn] @ Weff + bias_eff   (Wout folded in) — TM=64, 4 blocks/CU
    k_gemm<64><<<dim3(512, 2), 256, 0, stream>>>(xh, mbuf, 256, 256, w1t, 512, 512, bias_eff,
                                                 nullptr, 2, hbuf, nullptr, nullptr, nullptr,
                                                 nullptr, nullptr);
    k_ln_gelu<<<8192, 256, 0, stream>>>(hbuf, lng, lnb);
    // FFN2 + residual (f16 xh) -> fp32 out — TM=64, grid 512 = 2 blocks/CU
    k_gemm<64><<<dim3(512, 1), 256, 0, stream>>>(hbuf, hbuf, 1 << 30, 512, w2t, 512, 256, b2,
                                                 nullptr, 3, out, nullptr, xh, nullptr, nullptr,
                                                 nullptr);
}